// Round 13
// baseline (747.729 us; speedup 1.0000x reference)
//
#include <hip/hip_runtime.h>
#include <math.h>

typedef unsigned short u16;
typedef __attribute__((ext_vector_type(8))) short short8;
typedef __attribute__((ext_vector_type(4))) float f32x4;

// ---------------- problem constants ----------------
constexpr int NB   = 4096;   // B
constexpr int NU   = 6;      // U
constexpr int NIN  = 256;    // IN
constexpr int NH   = 600;    // H
constexpr int IKS  = 64;
constexpr int IVS  = 400;
constexpr int NCH  = 4;
constexpr int CVS  = 600;
constexpr int KTOP = 4;

constexpr int QKW  = 256;            // q(128)|k(128)
constexpr int VW   = NCH * CVS;      // 2400

// padded MFMA dims
constexpr int KG2   = 896;           // GRU K: [c0*x (256) | hs (600) | pad]
constexpr int HOFS2 = 256;           // hs starts here (8*32)
constexpr int NGATE = 640;           // 600 padded
constexpr int NROWS3= 3 * NGATE;     // 1920
constexpr int KXP   = 448;           // x2h k-pad (400 -> 7*64)
constexpr int KH    = 640;           // hnew K padded
constexpr int VN    = 2432;          // 2400 padded (19*128)
constexpr int BC    = 2048;          // chunk rows (in-place ctx)
constexpr int NCHUNK = NB / BC;      // 2

// ---------------- ws layout (float offsets) ----------------
constexpr long OFF_KV   = 0;                                   // f32 [NB][64] (k0)
constexpr long OFF_QRY  = OFF_KV   + (long)NB * IKS;           // f32 [NB][NU][64]
constexpr long OFF_C0   = OFF_QRY  + (long)NB * NU * IKS;
constexpr long OFF_C1   = OFF_C0   + (long)NB * NU;
constexpr long OFF_MASK = OFF_C1   + (long)NB * NU;
constexpr long OFF_QK   = OFF_MASK + (long)NB * NU;            // f32 [NB][NU][256]
constexpr long OFF_ATTW = OFF_QK   + (long)NB * NU * QKW;      // f32 [NB][NCH][NU][NU]
constexpr long OFF_HNBF = OFF_ATTW + (long)NB * NCH * NU * NU; // bf16 [NU][NB][640]
constexpr long OFF_WQK  = OFF_HNBF + (long)NU * NB * KH / 2;   // bf16 [NU][256][640]
constexpr long OFF_WV   = OFF_WQK  + (long)NU * QKW * KH / 2;  // bf16 [NU][2432][640]
constexpr long OFF_WOUT = OFF_WV   + (long)NU * VN * KH / 2;   // bf16 [NU][640][2432]
constexpr long OFF_WVB  = OFF_WOUT + (long)NU * NGATE * VN / 2;// bf16 [256][448]
constexpr long OFF_TVEC = OFF_WVB  + (long)256 * KXP / 2;      // f32 [NU][1920]
constexpr long OFF_CNT  = OFF_TVEC + (long)NU * NROWS3;        // int [NCHUNK][6] (16)
constexpr long OFF_BLIST= OFF_CNT  + 16;                       // int [NCHUNK][6][BC]
constexpr long OFF_WGRU2= OFF_BLIST+ (long)NCHUNK * NU * BC;   // bf16 [NU][1920][896]
constexpr long OFF_AGRU2= OFF_WGRU2+ (long)NU * NROWS3 * KG2/2;// bf16 [NU][NB][896]
// aliases: wgru_x (bf16 [NU][1920][448]) lives in AGRU2 space (dead before prep
// writes agru2); VBUF (bf16 [BC][NU][VN]) aliases WGRU2+AGRU2 (dead after gru).
constexpr long OFF_WGRUX = OFF_AGRU2;
constexpr long OFF_VBUF  = OFF_WGRU2;

// ---------------- helpers ----------------
__device__ __forceinline__ u16 f2bf(float f) {
    unsigned int x = __float_as_uint(f);
    x += 0x7FFFu + ((x >> 16) & 1u);
    return (u16)(x >> 16);
}
__device__ __forceinline__ float bf2f(u16 u) {
    return __uint_as_float(((unsigned int)u) << 16);
}
__device__ __forceinline__ void gl_lds16(const u16* g, u16* l) {
    __builtin_amdgcn_global_load_lds(
        (const __attribute__((address_space(1))) void*)g,
        (__attribute__((address_space(3))) void*)l, 16, 0, 0);
}

// counted-wait / barrier primitives (never drain vmcnt to 0 mid-loop)
#define WAITVM_(N) asm volatile("s_waitcnt vmcnt(" #N ")" ::: "memory")
#define WAITVM(N)  WAITVM_(N)
#define WAITLG()   asm volatile("s_waitcnt lgkmcnt(0)" ::: "memory")
#define SBAR()     do { __builtin_amdgcn_sched_barrier(0); \
                        __builtin_amdgcn_s_barrier();      \
                        __builtin_amdgcn_sched_barrier(0); } while (0)

// ================= weight transpose f32[K][N] -> bf16[n][k] =================
__global__ __launch_bounds__(256)
void wtrans_kernel(const float* __restrict__ src, long s_u, int s_ld, int s_colofs,
                   int Ksrc, int Nsub,
                   u16* __restrict__ dst, long d_u, int d_ld, int d_nofs, int d_kofs,
                   int gdiv, int s_gcol, int d_gnofs)
{
    __shared__ float tile[32][33];
    int z = blockIdx.z;
    int u = z, g = 0;
    if (gdiv > 1) { u = z / gdiv; g = z % gdiv; }
    const int k0 = blockIdx.x * 32, n0 = blockIdx.y * 32;
    const int t  = threadIdx.x;
    const int scol = s_colofs + g * s_gcol;
    const int dnof = d_nofs + g * d_gnofs;
    const float* S = src + (long)u * s_u;
    u16* D = dst + (long)u * d_u;
    #pragma unroll
    for (int r = 0; r < 4; r++) {
        int kk = r * 8 + (t >> 5), nn = t & 31;
        float v = 0.f;
        if (k0 + kk < Ksrc && n0 + nn < Nsub)
            v = S[(long)(k0 + kk) * s_ld + scol + n0 + nn];
        tile[kk][nn] = v;
    }
    __syncthreads();
    #pragma unroll
    for (int r = 0; r < 4; r++) {
        int nn = r * 8 + (t >> 5), kk = t & 31;
        if (n0 + nn < Nsub)
            D[(long)(dnof + n0 + nn) * d_ld + d_kofs + k0 + kk] = f2bf(tile[kk][nn]);
    }
}

// ================= Wv -> bf16 [256][448] (K-pad) =================
__global__ __launch_bounds__(256)
void wvbcast_kernel(const float* __restrict__ Wv, u16* __restrict__ wvb)
{
    int id = blockIdx.x * 256 + threadIdx.x;
    if (id >= 256 * KXP) return;
    int j = id / KXP, k = id % KXP;
    wvb[id] = (k < IVS) ? f2bf(Wv[(long)j * IVS + k]) : (u16)0;
}

// ================= t[r] = sum_k wgx[r][k] * bv[k]  (wave per row) ==========
__global__ __launch_bounds__(256)
void tvec_kernel(const u16* __restrict__ wgx, const float* __restrict__ bv,
                 float* __restrict__ tvec)
{
    const int wid  = threadIdx.x >> 6, lane = threadIdx.x & 63;
    const int r    = blockIdx.x * 4 + wid;
    if (r >= NU * NROWS3) return;
    const int k = lane * 8;
    float s = 0;
    if (k < IVS) {
        short8 v = *(const short8*)&wgx[(long)r * KXP + k];
        #pragma unroll
        for (int i = 0; i < 8; i++) s = fmaf(bf2f((u16)v[i]), bv[k + i], s);
    }
    #pragma unroll
    for (int off = 32; off > 0; off >>= 1) s += __shfl_down(s, off);
    if (lane == 0) tvec[r] = s;
}

// ============ G2: qry = hs @ Wq (z=0..5) | k0 = x @ Wk + bk (z=6) ===========
// z==6 block 0 also zeroes the compaction counters (runs before score_kernel).
__global__ __launch_bounds__(256)
void gemm_qry_kernel(const float* __restrict__ A,      // hs
                     const float* __restrict__ W,      // Wq
                     const float* __restrict__ x,
                     const float* __restrict__ Wk,
                     const float* __restrict__ bk,
                     float* __restrict__ C,            // qry
                     float* __restrict__ kv,           // k0
                     int* __restrict__ cnt)
{
    const int u  = blockIdx.z;
    const int m0 = blockIdx.x * 64;
    const int tid = threadIdx.x;
    const int tm = tid / 16, tn = tid % 16;
    constexpr int N = IKS;    // 64

    const bool isk0 = (u == NU);
    if (isk0 && blockIdx.x == 0 && tid < NCHUNK * NU) cnt[tid] = 0;
    const int  K   = isk0 ? NIN : NH;
    const long lda = isk0 ? NIN : (long)NU * NH;
    const float* Au = isk0 ? x : (A + (long)u * NH);
    const float* Wu = isk0 ? Wk : (W + (long)u * NH * N);

    __shared__ __align__(16) float As[32][72];
    __shared__ __align__(16) float Ws[32][68];
    float acc[4][4] = {};

    for (int k0 = 0; k0 < K; k0 += 32) {
        #pragma unroll
        for (int s2 = 0; s2 < 2; s2++) {
            int s = tid * 2 + s2;
            int row = s >> 3, kc = s & 7;
            float4 v = {0,0,0,0};
            if (k0 + kc*4 < K)
                v = *(const float4*)&Au[(long)(m0 + row) * lda + k0 + kc * 4];
            As[kc*4+0][row] = v.x; As[kc*4+1][row] = v.y;
            As[kc*4+2][row] = v.z; As[kc*4+3][row] = v.w;
        }
        #pragma unroll
        for (int s2 = 0; s2 < 2; s2++) {
            int s = tid * 2 + s2;
            int kr = s >> 4, c4 = s & 15;
            float4 v = {0,0,0,0};
            if (k0 + kr < K)
                v = *(const float4*)&Wu[(long)(k0 + kr) * N + c4 * 4];
            *(float4*)&Ws[kr][c4*4] = v;
        }
        __syncthreads();
        #pragma unroll
        for (int kk = 0; kk < 32; kk++) {
            float4 a4 = *(const float4*)&As[kk][tm*4];
            float4 w4 = *(const float4*)&Ws[kk][tn*4];
            float av[4] = {a4.x,a4.y,a4.z,a4.w}, wv[4] = {w4.x,w4.y,w4.z,w4.w};
            #pragma unroll
            for (int i = 0; i < 4; i++)
                #pragma unroll
                for (int j = 0; j < 4; j++)
                    acc[i][j] = fmaf(av[i], wv[j], acc[i][j]);
        }
        __syncthreads();
    }
    #pragma unroll
    for (int i = 0; i < 4; i++) {
        int row = m0 + tm*4 + i;
        #pragma unroll
        for (int j = 0; j < 4; j++) {
            int c = tn*4 + j;
            if (isk0) kv[(long)row*N + c] = acc[i][j] + bk[c];
            else      C[(long)row*(NU*IKS) + (long)u*IKS + c] = acc[i][j];
        }
    }
}

// ================= K3: scores / top-k mask / compaction lists ==============
__global__ __launch_bounds__(64)
void score_kernel(const float* __restrict__ qry, const float* __restrict__ kv,
                  const float* __restrict__ bk,
                  float* __restrict__ c0, float* __restrict__ c1,
                  float* __restrict__ maskf,
                  int* __restrict__ cnt, int* __restrict__ blist)
{
    const int b = blockIdx.x;
    const int t = threadIdx.x;
    __shared__ float s0s[NU], s1s[NU];

    float k0v = kv[(long)b*IKS + t];
    float bkv = bk[t];
    for (int u = 0; u < NU; u++) {
        float q  = qry[((long)b*NU + u)*IKS + t];
        float p0 = q * k0v, p1 = q * bkv;
        #pragma unroll
        for (int off = 32; off > 0; off >>= 1) {
            p0 += __shfl_down(p0, off);
            p1 += __shfl_down(p1, off);
        }
        if (t == 0) { s0s[u] = p0 * 0.125f; s1s[u] = p1 * 0.125f; }
    }
    __syncthreads();
    if (t < NU) {
        int u = t;
        float su = s0s[u];
        int rank = 0;
        #pragma unroll
        for (int j = 0; j < NU; j++) {
            float sj = s0s[j];
            if (sj > su || (sj == su && j < u)) rank++;
        }
        float m = (rank < KTOP) ? 1.0f : 0.0f;
        float a = s0s[u], bb = s1s[u];
        float mx = fmaxf(a, bb);
        float e0 = expf(a - mx), e1 = expf(bb - mx);
        float p0 = e0 / (e0 + e1);
        c0[(long)b*NU + u]    = m * p0;
        c1[(long)b*NU + u]    = m * (1.0f - p0);
        maskf[(long)b*NU + u] = m;
        if (m > 0.5f) {
            int ch  = b / BC;
            int pos = atomicAdd(&cnt[ch*NU + u], 1);
            blist[((long)ch*NU + u)*BC + pos] = b;
        }
    }
}

// ================= out = hs for unmasked rows (float4 copy) ================
__global__ __launch_bounds__(256)
void copy_unmasked_kernel(const float* __restrict__ hs,
                          const float* __restrict__ maskf,
                          float* __restrict__ out)
{
    long id = (long)blockIdx.x * 256 + threadIdx.x;
    const long total = (long)NB * NU * (NH / 4);
    if (id >= total) return;
    int c4 = (int)(id % (NH / 4));
    int bu = (int)(id / (NH / 4));
    if (maskf[bu] < 0.5f) {
        long o = (long)bu * NH + c4 * 4;
        *(float4*)&out[o] = *(const float4*)&hs[o];
    }
}

// ================= prep A for GRU GEMM: [c0*x | hs | 0] bf16 ================
__global__ __launch_bounds__(256)
void prep_gruA_kernel(const float* __restrict__ x, const float* __restrict__ hs,
                      const float* __restrict__ c0, u16* __restrict__ Ag)
{
    long id = (long)blockIdx.x * 256 + threadIdx.x;
    const long total = (long)NU * NB * (KG2 / 8);
    if (id >= total) return;
    int k8 = (int)(id % (KG2 / 8));
    int b  = (int)((id / (KG2 / 8)) % NB);
    int u  = (int)(id / ((long)(KG2 / 8) * NB));
    int k  = k8 * 8;
    u16 o[8];
    if (k < HOFS2) {
        float cv0 = c0[(long)b*NU + u];
        const float* xp = x + (long)b*NIN + k;
        #pragma unroll
        for (int i = 0; i < 8; i++) o[i] = f2bf(cv0 * xp[i]);
    } else if (k < HOFS2 + NH) {
        const float* hp = hs + ((long)b*NU + u)*NH + (k - HOFS2);
        #pragma unroll
        for (int i = 0; i < 8; i++) o[i] = f2bf(hp[i]);
    } else {
        #pragma unroll
        for (int i = 0; i < 8; i++) o[i] = 0;
    }
    *(short8*)&Ag[id * 8] = *(const short8*)o;
}

// ================= GRU MFMA (3 gates; K=896; BK=32, 3-buf, depth-1) =========
__global__ __launch_bounds__(256, 3)
void gru_mfma_kernel(const u16* __restrict__ Ag, const u16* __restrict__ Wg,
                     const float* __restrict__ tvec, const float* __restrict__ maskf,
                     const float* __restrict__ hs, u16* __restrict__ hnbf)
{
    const int u  = blockIdx.z;
    const int m0 = blockIdx.x * 128;
    const int n0 = blockIdx.y * 32;
    const int tid = threadIdx.x;
    const int wid = tid >> 6, lane = tid & 63;
    const int wm = wid >> 1, wn = wid & 1;
    const int lrow = lane & 15, lkq = lane >> 4;
    const int srow = lane >> 2;                               // 0..15
    const int scs  = (((lane & 3) ^ ((lane >> 3) & 3)) * 8);  // swizzled src chunk
    const int cofs = ((lkq ^ ((lrow >> 1) & 3)) * 8);         // read-side key

    __shared__ __align__(16) u16 As[3][128 * 32];
    __shared__ __align__(16) u16 Bs[3][128 * 32];

    const u16* Au = Ag + (long)u * NB * KG2;
    const u16* Wu = Wg + (long)u * NROWS3 * KG2;

    f32x4 aR[4], aI[4], aNX[4], aNH[4];
    #pragma unroll
    for (int m = 0; m < 4; m++) {
        aR[m] = (f32x4){0,0,0,0}; aI[m] = (f32x4){0,0,0,0};
        aNX[m] = (f32x4){0,0,0,0}; aNH[m] = (f32x4){0,0,0,0};
    }

#define GSTAGE(BUF, T) do {                                                   \
        const long kk0 = (long)(T) * 32;                                      \
        _Pragma("unroll")                                                     \
        for (int i2 = 0; i2 < 2; i2++) {                                      \
            int R = wid*32 + i2*16;                                           \
            int row = R + srow;                                               \
            gl_lds16(Au + (long)(m0 + row)*KG2 + kk0 + scs,                   \
                     &As[BUF][R * 32]);                                       \
            int g = row >> 5; if (g > 2) g = 2;  /* pad rows: L2-hot dup */   \
            int rn = row & 31;                                                \
            gl_lds16(Wu + ((long)g*NGATE + n0 + rn)*KG2 + kk0 + scs,          \
                     &Bs[BUF][R * 32]);                                       \
        }                                                                     \
    } while (0)

#define GCOMPUTE(BUF, T) do {                                                 \
        __builtin_amdgcn_s_setprio(1);                                        \
        short8 af[4], bR, bI, bN;                                             \
        _Pragma("unroll")                                                     \
        for (int m = 0; m < 4; m++)                                           \
            af[m] = *(const short8*)&As[BUF][(wm*64 + m*16 + lrow)*32 + cofs];\
        {                                                                     \
            int nr = wn*16 + lrow;                                            \
            bR = *(const short8*)&Bs[BUF][(0*32 + nr)*32 + cofs];             \
            bI = *(const short8*)&Bs[BUF][(1*32 + nr)*32 + cofs];             \
            bN = *(const short8*)&Bs[BUF][(2*32 + nr)*32 + cofs];             \
        }                                                                     \
        _Pragma("unroll")                                                     \
        for (int m = 0; m < 4; m++) {                                         \
            aR[m] = __builtin_amdgcn_mfma_f32_16x16x32_bf16(af[m], bR, aR[m], 0, 0, 0); \
            aI[m] = __builtin_amdgcn_mfma_f32_16x16x32_bf16(af[m], bI, aI[m], 0, 0, 0); \
        }                                                                     \
        if ((T) < HOFS2/32) {                                                 \
            _Pragma("unroll")                                                 \
            for (int m = 0; m < 4; m++)                                       \
                aNX[m] = __builtin_amdgcn_mfma_f32_16x16x32_bf16(af[m], bN, aNX[m], 0, 0, 0); \
        } else {                                                              \
            _Pragma("unroll")                                                 \
            for (int m = 0; m < 4; m++)                                       \
                aNH[m] = __builtin_amdgcn_mfma_f32_16x16x32_bf16(af[m], bN, aNH[m], 0, 0, 0); \
        }                                                                     \
        __builtin_amdgcn_s_setprio(0);                                        \
    } while (0)

    constexpr int KSTEPS = KG2 / 32;   // 28
    GSTAGE(0, 0);
    int bc = 0, bn = 1;
    for (int t = 0; t < KSTEPS - 1; ++t) {
        GSTAGE(bn, t + 1);
        WAITVM(4); SBAR();
        GCOMPUTE(bc, t);
        bc = bn; bn = (bn == 2) ? 0 : bn + 1;
    }
    WAITVM(0); SBAR();
    GCOMPUTE(bc, KSTEPS - 1);
#undef GCOMPUTE
#undef GSTAGE

    const int col = n0 + wn*16 + lrow;
    float tR = 0, tI = 0, tN = 0;
    if (col < NH) {
        tR = tvec[(long)u*NROWS3 + col];
        tI = tvec[(long)u*NROWS3 + NGATE + col];
        tN = tvec[(long)u*NROWS3 + 2*NGATE + col];
    }
    #pragma unroll
    for (int m = 0; m < 4; m++) {
        #pragma unroll
        for (int r = 0; r < 4; r++) {
            int row = m0 + wm*64 + m*16 + lkq*4 + r;   // b
            u16 ov = 0;
            if (col < NH) {
                float mk = maskf[(long)row*NU + u];
                float rg = 1.0f / (1.0f + expf(-(aR[m][r] + mk*tR)));
                float ig = 1.0f / (1.0f + expf(-(aI[m][r] + mk*tI)));
                float ng = tanhf(aNX[m][r] + mk*tN + rg * aNH[m][r]);
                float h  = hs[((long)row*NU + u)*NH + col];
                ov = f2bf(ng + ig * (h - ng));
            }
            hnbf[(long)u*NB*KH + (long)row*KH + col] = ov;
        }
    }
}

// ================= generic 128x128 bf16 MFMA GEMM (BK=64, 2-buf counted) ====
// EPI=0: f32 store; EPI=2: bf16 store
template<int EPI>
__global__ __launch_bounds__(256, 2)
void mfgemm_kernel(const u16* __restrict__ A, long sAu, int lda,
                   const u16* __restrict__ Bw, long sBu, int ldb,
                   float* __restrict__ Cf, u16* __restrict__ C16,
                   long sCu, int ldc, int ksteps)      // ksteps in BK=64 units
{
    const int u  = blockIdx.z;
    const int m0 = blockIdx.x * 128;
    const int n0 = blockIdx.y * 128;
    const int tid = threadIdx.x;
    const int wid = tid >> 6, lane = tid & 63;
    const int wm = wid >> 1, wn = wid & 1;
    const int lrow = lane & 15, lkq = lane >> 4;
    const int l8 = lane & 7, lr8 = lane >> 3;
    const int rsw = lrow & 7;

    __shared__ __align__(16) u16 As[2][128 * 64];
    __shared__ __align__(16) u16 Bs[2][128 * 64];

    const u16* Au = A + (long)u * sAu;
    const u16* Bu = Bw + (long)u * sBu;

    f32x4 acc[4][4];
    #pragma unroll
    for (int m = 0; m < 4; m++)
        #pragma unroll
        for (int n = 0; n < 4; n++) acc[m][n] = (f32x4){0,0,0,0};

#define MSTAGE(BUF, KS) do {                                                  \
        const long kk0 = (long)(KS) * 64;                                     \
        _Pragma("unroll")                                                     \
        for (int i2 = 0; i2 < 4; i2++) {                                      \
            int rw = i2*32 + wid*8 + lr8;                                     \
            int co = ((l8 ^ (rw & 7)) * 8);                                   \
            gl_lds16(Au + (long)(m0 + rw)*lda + kk0 + co,                     \
                     &As[BUF][(i2*32 + wid*8) * 64]);                         \
            gl_lds16(Bu + (long)(n0 + rw)*ldb + kk0 + co,                     \
                     &Bs[BUF][(i2*32 + wid*8) * 64]);                         \
        }                                                                     \
    } while (0)

#define MCOMPUTE(BUF) do {                                                    \
        __builtin_amdgcn_s_setprio(1);                                        \
        _Pragma("unroll")                                                     \
        for (int ks2 = 0; ks2 < 2; ks2++) {                                   \
            const int cofs = (((ks2*4 + lkq) ^ rsw) * 8);                     \
            short8 af[4], bfr[4];                                             \
            _Pragma("unroll")                                                 \
            for (int m = 0; m < 4; m++)                                       \
                af[m] = *(const short8*)&As[BUF][(wm*64 + m*16 + lrow)*64 + cofs]; \
            _Pragma("unroll")                                                 \
            for (int n = 0; n < 4; n++)                                       \
                bfr[n] = *(const short8*)&Bs[BUF][(wn*64 + n*16 + lrow)*64 + cofs]; \
            _Pragma("unroll")                                                 \
            for (int m = 0; m < 4; m++)                                       \
                _Pragma("unroll")                                             \
                for (int n = 0; n < 4; n++)                                   \
                    acc[m][n] = __builtin_amdgcn_mfma_f32_16x16x32_bf16(af[m], bfr[n], acc[m][n], 0, 0, 0); \
        }                                                                     \
        __builtin_amdgcn_s_setprio(0);                                        \
    } while (0)

#define MPH(BUF, T, W) do {                                                   \
        if ((T) + 1 < ksteps) MSTAGE((BUF)^1, (T)+1);                         \
        WAITVM(W); SBAR();                                                    \
        MCOMPUTE(BUF);                                                        \
        WAITLG(); SBAR();                                                     \
    } while (0)

    MSTAGE(0, 0);
    int t = 0;
    for (; t + 2 < ksteps; t += 2) { MPH(0, t, 8); MPH(1, t+1, 8); }
    if (t + 2 == ksteps) { MPH(0, t, 8); MPH(1, t+1, 0); }
    else                 { MPH(0, t, 0); }   // odd tail (used by M-GEMM, ksteps=7)
#undef MPH
#undef MCOMPUTE
#undef MSTAGE

    #pragma unroll
    for (int m = 0; m < 4; m++) {
        #pragma unroll
        for (int r = 0; r < 4; r++) {
            int row = m0 + wm*64 + m*16 + lkq*4 + r;
            #pragma unroll
            for (int n = 0; n < 4; n++) {
                int col = n0 + wn*64 + n*16 + lrow;
                float v = acc[m][n][r];
                if (EPI == 0) Cf[(long)u*sCu + (long)row*ldc + col] = v;
                else          C16[(long)u*sCu + (long)row*ldc + col] = f2bf(v);
            }
        }
    }
}

// ======= out-GEMM, COMPACTED over masked rows (gathered A, BK=64) ==========
// grid (BC/128, NGATE/128, NU); block-uniform early-exit on count.
__global__ __launch_bounds__(256, 2)
void outc_kernel(const u16* __restrict__ vcbuf,   // [BC][NU][VN] bf16 (ctx)
                 const u16* __restrict__ wout,    // [NU][NGATE][VN]
                 const int* __restrict__ cnt, const int* __restrict__ blist,
                 const u16* __restrict__ hnbf, float* __restrict__ out,
                 int ch)
{
    const int u  = blockIdx.z;
    const int m0 = blockIdx.x * 128;
    const int count = cnt[ch*NU + u];
    if (m0 >= count) return;
    const int* bl = blist + ((long)ch*NU + u)*BC;
    const int bbase = ch * BC;
    const int n0 = blockIdx.y * 128;
    const int tid = threadIdx.x;
    const int wid = tid >> 6, lane = tid & 63;
    const int wm = wid >> 1, wn = wid & 1;
    const int lrow = lane & 15, lkq = lane >> 4;
    const int l8 = lane & 7, lr8 = lane >> 3;
    const int rsw = lrow & 7;
    constexpr int ksteps = VN / 64;   // 38 (even)

    __shared__ __align__(16) u16 As[2][128 * 64];
    __shared__ __align__(16) u16 Bs[2][128 * 64];

    // pre-gather staged-row b's (4 rows per lane, fixed across k-loop)
    const u16* arp[4];
    #pragma unroll
    for (int i2 = 0; i2 < 4; i2++) {
        int lr = m0 + i2*32 + wid*8 + lr8;
        if (lr >= count) lr = count - 1;          // benign duplicate
        int b = bl[lr];
        arp[i2] = vcbuf + ((long)(b - bbase)*NU + u)*VN;
    }
    const u16* Bu = wout + (long)u * NGATE * VN;

    f32x4 acc[4][4];
    #pragma unroll
    for (int m = 0; m < 4; m++)
        #pragma unroll
        for (int n = 0; n < 4; n++) acc[m][n] = (f32x4){0,0,0,0};

#define OSTAGE(BUF, KS) do {                                                  \
        const long kk0 = (long)(KS) * 64;                                     \
        _Pragma("unroll")                                                     \
        for (int i2 = 0; i2 < 4; i2++) {                                      \
            int rw = i2*32 + wid*8 + lr8;                                     \
            int co = ((l8 ^ (rw & 7)) * 8);                                   \
            gl_lds16(arp[i2] + kk0 + co, &As[BUF][(i2*32 + wid*8) * 64]);     \
            gl_lds16(Bu + (long)(n0 + rw)*VN + kk0 + co,                      \
                     &Bs[BUF][(i2*32 + wid*8) * 64]);                         \
        }                                                                     \
    } while (0)

#define OCOMPUTE(BUF) do {                                                    \
        __builtin_amdgcn_s_setprio(1);                                        \
        _Pragma("unroll")                                                     \
        for (int ks2 = 0; ks2 < 2; ks2++) {                                   \
            const int cofs = (((ks2*4 + lkq) ^ rsw) * 8);                     \
            short8 af[4], bfr[4];                                             \
            _Pragma("unroll")                                                 \
            for (int m = 0; m < 4; m++)                                       \
                af[m] = *(const short8*)&As[BUF][(wm*64 + m*16 + lrow)*64 + cofs]; \
            _Pragma("unroll")                                                 \
            for (int n = 0; n < 4; n++)                                       \
                bfr[n] = *(const short8*)&Bs[BUF][(wn*64 + n*16 + lrow)*64 + cofs]; \
            _Pragma("unroll")                                                 \
            for (int m = 0; m < 4; m++)                                       \
                _Pragma("unroll")                                             \
                for (int n = 0; n < 4; n++)                                   \
                    acc[m][n] = __builtin_amdgcn_mfma_f32_16x16x32_bf16(af[m], bfr[n], acc[m][n], 0, 0, 0); \
        }                                                                     \
        __builtin_amdgcn_s_setprio(0);                                        \
    } while (0)

    OSTAGE(0, 0);
    int t = 0;
    for (; t + 2 < ksteps; t += 2) {
        if (t + 1 < ksteps) {}
        OSTAGE(1, t + 1); WAITVM(8); SBAR(); OCOMPUTE(0); WAITLG(); SBAR();
        if (t + 2 < ksteps) OSTAGE(0, t + 2);
        WAITVM(8); SBAR(); OCOMPUTE(1); WAITLG(); SBAR();
    }
    // ksteps even: t == ksteps-2 here
    OSTAGE(1, t + 1); WAITVM(8); SBAR(); OCOMPUTE(0); WAITLG(); SBAR();
    WAITVM(0); SBAR(); OCOMPUTE(1); WAITLG(); SBAR();
#undef OCOMPUTE
#undef OSTAGE

    #pragma unroll
    for (int m = 0; m < 4; m++) {
        #pragma unroll
        for (int r = 0; r < 4; r++) {
            int lr = m0 + wm*64 + m*16 + lkq*4 + r;
            if (lr >= count) continue;
            int b = bl[lr];
            #pragma unroll
            for (int n = 0; n < 4; n++) {
                int col = n0 + wn*64 + n*16 + lrow;
                if (col < NH) {
                    long o = ((long)b*NU + u)*NH + col;
                    float hv = bf2f(hnbf[(long)u*NB*KH + (long)b*KH + col]);
                    out[o] = acc[m][n][r] + hv;
                }
            }
        }
    }
}

// ================= K7: attention weights (one block per b) =================
__global__ __launch_bounds__(256)
void attw_kernel(const float* __restrict__ qk, const float* __restrict__ maskf,
                 float* __restrict__ attw)
{
    const int b = blockIdx.x;
    const int t = threadIdx.x;
    __shared__ float qks[NU * QKW];              // 6KB
    __shared__ float lg[NCH][NU][NU];

    for (int i = t; i < NU * QKW / 4; i += 256)
        *(float4*)&qks[i * 4] = *(const float4*)&qk[(long)b * NU * QKW + i * 4];
    __syncthreads();

    if (t < NCH * NU * NU) {
        int h = t / 36, uq = (t % 36) / 6, un = t % 6;
        const float* qp = &qks[uq * QKW + h * 32];
        const float* kp = &qks[un * QKW + 128 + h * 32];
        float s = 0;
        #pragma unroll
        for (int i = 0; i < 32; i++) s = fmaf(qp[i], kp[i], s);
        lg[h][uq][un] = s * 0.17677669529663687f;
    }
    __syncthreads();
    if (t < NCH * NU) {
        int h = t / NU, uq = t % NU;
        float mx = -1e30f;
        #pragma unroll
        for (int n = 0; n < NU; n++) mx = fmaxf(mx, lg[h][uq][n]);
        float e[NU], se = 0;
        #pragma unroll
        for (int n = 0; n < NU; n++) { e[n] = expf(lg[h][uq][n] - mx); se += e[n]; }
        float m = maskf[(long)b*NU + uq];
        float inv = m / se;
        #pragma unroll
        for (int n = 0; n < NU; n++)
            attw[(((long)b*NCH + h)*NU + uq)*NU + n] = e[n] * inv;
    }
}

// ================= ctx = att @ v, IN-PLACE on the v buffer ==================
__global__ __launch_bounds__(256)
void ctx2_kernel(const float* __restrict__ attw, u16* vc, int bbase)
{
    __shared__ float att_s[32][NCH * NU * NU];   // [bl][h*36+u*6+n] = 144
    const int c0 = blockIdx.x * 64;
    const int b0 = blockIdx.y * 32;
    const int tid = threadIdx.x;

    for (int i = tid; i < 32 * 144; i += 256) {
        int bl = i / 144, j = i % 144;
        att_s[bl][j] = attw[(long)(bbase + b0 + bl) * 144 + j];
    }
    __syncthreads();

    const int bl = tid >> 3;
    const int c  = c0 + (tid & 7) * 8;
    const long rowbase = (long)(b0 + bl) * NU;   // chunk-local

    if (c >= VW) {   // pad columns -> zero
        short8 z = {0,0,0,0,0,0,0,0};
        #pragma unroll
        for (int u = 0; u < NU; u++)
            *(short8*)&vc[(rowbase + u) * VN + c] = z;
        return;
    }
    const int h = c / CVS;
    const float* aw = &att_s[bl][h * 36];

    float vf[NU][8];
    #pragma unroll
    for (int n = 0; n < NU; n++) {
        short8 vv = *(const short8*)&vc[(rowbase + n) * VN + c];
        #pragma unroll
        for (int i = 0; i < 8; i++) vf[n][i] = bf2f((u16)vv[i]);
    }
    #pragma unroll
    for (int u = 0; u < NU; u++) {
        float acc[8] = {};
        #pragma unroll
        for (int n = 0; n < NU; n++) {
            float a = aw[u * 6 + n];
            #pragma unroll
            for (int i = 0; i < 8; i++) acc[i] = fmaf(a, vf[n][i], acc[i]);
        }
        short8 o;
        #pragma unroll
        for (int i = 0; i < 8; i++) o[i] = (short)f2bf(acc[i]);
        *(short8*)&vc[(rowbase + u) * VN + c] = o;
    }
}

// ================= host launcher =================
extern "C" void kernel_launch(void* const* d_in, const int* in_sizes, int n_in,
                              void* d_out, int out_size, void* d_ws, size_t ws_size,
                              hipStream_t stream)
{
    const float* x    = (const float*)d_in[0];
    const float* hs   = (const float*)d_in[1];
    const float* Wk   = (const float*)d_in[2];
    const float* bk   = (const float*)d_in[3];
    const float* Wv   = (const float*)d_in[4];
    const float* bv   = (const float*)d_in[5];
    const float* Wq   = (const float*)d_in[6];
    const float* x2h  = (const float*)d_in[7];
    const float* h2h  = (const float*)d_in[8];
    const float* Wq_  = (const float*)d_in[9];
    const float* Wk_  = (const float*)d_in[10];
    const float* Wv_  = (const float*)d_in[11];
    const float* Wout = (const float*)d_in[12];
    float* out = (float*)d_out;
    float* ws  = (float*)d_ws;

    float* kv    = ws + OFF_KV;
    float* qry   = ws + OFF_QRY;
    float* c0b   = ws + OFF_C0;
    float* c1b   = ws + OFF_C1;
    float* maskf = ws + OFF_MASK;
    float* qk    = ws + OFF_QK;
    float* attw  = ws + OFF_ATTW;
    u16*   hnbf  = (u16*)(ws + OFF_HNBF);
    u16*   wqk   = (u16*)(ws + OFF_WQK);
    u16*   wv    = (u16*)(ws + OFF_WV);
    u16*   wout  = (u16*)(ws + OFF_WOUT);
    u16*   wvb   = (u16*)(ws + OFF_WVB);
    float* tvec  = ws + OFF_TVEC;
    int*   cnt   = (int*)(ws + OFF_CNT);
    int*   blist = (int*)(ws + OFF_BLIST);
    u16*   wgru2 = (u16*)(ws + OFF_WGRU2);
    u16*   agru2 = (u16*)(ws + OFF_AGRU2);
    u16*   wgx   = (u16*)(ws + OFF_WGRUX);  // aliased with agru2 (dead first)
    u16*   vcbuf = (u16*)(ws + OFF_VBUF);   // aliases wgru2+agru2 (chunk phase)

    // 1) weight conversions/transposes (k-pads zero-written by wtrans)
    wtrans_kernel<<<dim3(20, 4, NU), 256, 0, stream>>>(
        Wq_, (long)NH*128, 128, 0, NH, 128, wqk, (long)QKW*KH, KH, 0, 0, 1, 0, 0);
    wtrans_kernel<<<dim3(20, 4, NU), 256, 0, stream>>>(
        Wk_, (long)NH*128, 128, 0, NH, 128, wqk, (long)QKW*KH, KH, 128, 0, 1, 0, 0);
    wtrans_kernel<<<dim3(20, 75, NU), 256, 0, stream>>>(
        Wv_, (long)NH*VW, VW, 0, NH, VW, wv, (long)VN*KH, KH, 0, 0, 1, 0, 0);
    wtrans_kernel<<<dim3(76, 19, NU), 256, 0, stream>>>(
        Wout, (long)VW*NH, NH, 0, VW, NH, wout, (long)NGATE*VN, VN, 0, 0, 1, 0, 0);
    // x2h^T -> wgx [NU][1920][448]  (g folded into grid.z)
    wtrans_kernel<<<dim3(KXP/32, 19, NU*3), 256, 0, stream>>>(
        x2h, (long)IVS*3*NH, 3*NH, 0, IVS, NH,
        wgx, (long)NROWS3*KXP, KXP, 0, 0, 3, NH, NGATE);
    // h2h^T -> wgru2 k 256..895
    wtrans_kernel<<<dim3(20, 19, NU*3), 256, 0, stream>>>(
        h2h, (long)NH*3*NH, 3*NH, 0, NH, NH,
        wgru2, (long)NROWS3*KG2, KG2, 0, HOFS2, 3, NH, NGATE);
    // Wv -> bf16 [256][448]
    wvbcast_kernel<<<(256*KXP + 255)/256, 256, 0, stream>>>(Wv, wvb);
    // M^T[u] = x2h^T @ Wv : wgru2 k 0..255   (ksteps = 7, odd tail)
    mfgemm_kernel<2><<<dim3(NROWS3/128, 2, NU), 256, 0, stream>>>(
        wgx, (long)NROWS3*KXP, KXP, wvb, 0L, KXP,
        nullptr, wgru2, (long)NROWS3*KG2, KG2, KXP/64);
    // t[u] = x2h^T @ bv  (wave per row)
    tvec_kernel<<<(NU*NROWS3 + 3)/4, 256, 0, stream>>>(wgx, bv, tvec);

    // 2) f32 front-end: qry (z=0..5) + k0 (z=6, zeroes cnt) fused
    gemm_qry_kernel<<<dim3(NB/64, 1, NU + 1), 256, 0, stream>>>(
        hs, Wq, x, Wk, bk, qry, kv, cnt);
    score_kernel<<<NB, 64, 0, stream>>>(qry, kv, bk, c0b, c1b, maskf, cnt, blist);
    copy_unmasked_kernel<<<(unsigned)(((long)NB*NU*(NH/4) + 255)/256), 256, 0, stream>>>(
        hs, maskf, out);

    // 3) GRU A prep (AFTER M-GEMM+tvec: agru2 overwrites wgx) + GRU MFMA
    {
        long total = (long)NU * NB * (KG2/8);
        prep_gruA_kernel<<<(unsigned)((total + 255)/256), 256, 0, stream>>>(
            x, hs, c0b, agru2);
    }
    gru_mfma_kernel<<<dim3(NB/128, NGATE/32, NU), 256, 0, stream>>>(
        agru2, wgru2, tvec, maskf, hs, hnbf);

    // 4) qk projection (MFMA) + attention weights
    mfgemm_kernel<0><<<dim3(NB/128, QKW/128, NU), 256, 0, stream>>>(
        hnbf, (long)NB*KH, KH, wqk, (long)QKW*KH, KH,
        qk, nullptr, (long)QKW, NU*QKW, KH/64);
    attw_kernel<<<NB, 256, 0, stream>>>(qk, maskf, attw);

    // 5) chunked v / ctx(in-place) / out-compact  (BC=2048, 2 chunks)
    for (int ch = 0; ch < NCHUNK; ch++) {
        mfgemm_kernel<2><<<dim3(BC/128, VN/128, NU), 256, 0, stream>>>(
            hnbf + (long)ch*BC*KH, (long)NB*KH, KH, wv, (long)VN*KH, KH,
            nullptr, vcbuf, (long)VN, NU*VN, KH/64);
        ctx2_kernel<<<dim3(VN/64, BC/32), 256, 0, stream>>>(
            attw, vcbuf, ch*BC);
        outc_kernel<<<dim3(BC/128, NGATE/128, NU), 256, 0, stream>>>(
            vcbuf, wout, cnt, blist, hnbf, out, ch);
    }
}

// Round 14
// 682.312 us; speedup vs baseline: 1.0959x; 1.0959x over previous
//
#include <hip/hip_runtime.h>
#include <math.h>

typedef unsigned short u16;
typedef __attribute__((ext_vector_type(8))) short short8;
typedef __attribute__((ext_vector_type(4))) float f32x4;

// ---------------- problem constants ----------------
constexpr int NB   = 4096;   // B
constexpr int NU   = 6;      // U
constexpr int NIN  = 256;    // IN
constexpr int NH   = 600;    // H
constexpr int IKS  = 64;
constexpr int IVS  = 400;
constexpr int NCH  = 4;
constexpr int CVS  = 600;
constexpr int KTOP = 4;

constexpr int QKW  = 256;            // q(128)|k(128)
constexpr int VW   = NCH * CVS;      // 2400

// padded MFMA dims
constexpr int KG2   = 896;           // GRU K: [c0*x (256) | hs (600) | pad]
constexpr int HOFS2 = 256;           // hs starts here (8*32)
constexpr int NGATE = 640;           // 600 padded
constexpr int NROWS3= 3 * NGATE;     // 1920
constexpr int KXP   = 448;           // x2h k-pad (400 -> 7*64)
constexpr int KH    = 640;           // hnew K padded
constexpr int VN    = 2432;          // 2400 padded (19*128)
constexpr int BC    = 2048;          // chunk rows (in-place ctx)
constexpr int NCHUNK = NB / BC;      // 2

// ---------------- ws layout (float offsets) ----------------
constexpr long OFF_KV   = 0;                                   // f32 [NB][64] (k0)
constexpr long OFF_QRY  = OFF_KV   + (long)NB * IKS;           // f32 [NB][NU][64]
constexpr long OFF_C0   = OFF_QRY  + (long)NB * NU * IKS;
constexpr long OFF_C1   = OFF_C0   + (long)NB * NU;
constexpr long OFF_MASK = OFF_C1   + (long)NB * NU;
constexpr long OFF_QK   = OFF_MASK + (long)NB * NU;            // f32 [NB][NU][256]
constexpr long OFF_ATTW = OFF_QK   + (long)NB * NU * QKW;      // f32 [NB][NCH][NU][NU]
constexpr long OFF_HNBF = OFF_ATTW + (long)NB * NCH * NU * NU; // bf16 [NU][NB][640]
constexpr long OFF_WQK  = OFF_HNBF + (long)NU * NB * KH / 2;   // bf16 [NU][256][640]
constexpr long OFF_WV   = OFF_WQK  + (long)NU * QKW * KH / 2;  // bf16 [NU][2432][640]
constexpr long OFF_WOUT = OFF_WV   + (long)NU * VN * KH / 2;   // bf16 [NU][640][2432]
constexpr long OFF_WVB  = OFF_WOUT + (long)NU * NGATE * VN / 2;// bf16 [256][448]
constexpr long OFF_TVEC = OFF_WVB  + (long)256 * KXP / 2;      // f32 [NU][1920]
constexpr long OFF_WGRU2= OFF_TVEC + (long)NU * NROWS3;        // bf16 [NU][1920][896]
constexpr long OFF_AGRU2= OFF_WGRU2+ (long)NU * NROWS3 * KG2/2;// bf16 [NU][NB][896]
// aliases: wgru_x (bf16 [NU][1920][448]) lives in AGRU2 space (dead before prep
// writes agru2); VBUF (bf16 [BC][NU][VN]) aliases WGRU2+AGRU2 (dead after gru).
constexpr long OFF_WGRUX = OFF_AGRU2;
constexpr long OFF_VBUF  = OFF_WGRU2;

// ---------------- helpers ----------------
__device__ __forceinline__ u16 f2bf(float f) {
    unsigned int x = __float_as_uint(f);
    x += 0x7FFFu + ((x >> 16) & 1u);
    return (u16)(x >> 16);
}
__device__ __forceinline__ float bf2f(u16 u) {
    return __uint_as_float(((unsigned int)u) << 16);
}
__device__ __forceinline__ void gl_lds16(const u16* g, u16* l) {
    __builtin_amdgcn_global_load_lds(
        (const __attribute__((address_space(1))) void*)g,
        (__attribute__((address_space(3))) void*)l, 16, 0, 0);
}

// counted-wait / barrier primitives (never drain vmcnt to 0 mid-loop)
#define WAITVM_(N) asm volatile("s_waitcnt vmcnt(" #N ")" ::: "memory")
#define WAITVM(N)  WAITVM_(N)
#define WAITLG()   asm volatile("s_waitcnt lgkmcnt(0)" ::: "memory")
#define SBAR()     do { __builtin_amdgcn_sched_barrier(0); \
                        __builtin_amdgcn_s_barrier();      \
                        __builtin_amdgcn_sched_barrier(0); } while (0)

// ================= weight transpose f32[K][N] -> bf16[n][k] =================
__global__ __launch_bounds__(256)
void wtrans_kernel(const float* __restrict__ src, long s_u, int s_ld, int s_colofs,
                   int Ksrc, int Nsub,
                   u16* __restrict__ dst, long d_u, int d_ld, int d_nofs, int d_kofs,
                   int gdiv, int s_gcol, int d_gnofs)
{
    __shared__ float tile[32][33];
    int z = blockIdx.z;
    int u = z, g = 0;
    if (gdiv > 1) { u = z / gdiv; g = z % gdiv; }
    const int k0 = blockIdx.x * 32, n0 = blockIdx.y * 32;
    const int t  = threadIdx.x;
    const int scol = s_colofs + g * s_gcol;
    const int dnof = d_nofs + g * d_gnofs;
    const float* S = src + (long)u * s_u;
    u16* D = dst + (long)u * d_u;
    #pragma unroll
    for (int r = 0; r < 4; r++) {
        int kk = r * 8 + (t >> 5), nn = t & 31;
        float v = 0.f;
        if (k0 + kk < Ksrc && n0 + nn < Nsub)
            v = S[(long)(k0 + kk) * s_ld + scol + n0 + nn];
        tile[kk][nn] = v;
    }
    __syncthreads();
    #pragma unroll
    for (int r = 0; r < 4; r++) {
        int nn = r * 8 + (t >> 5), kk = t & 31;
        if (n0 + nn < Nsub)
            D[(long)(dnof + n0 + nn) * d_ld + d_kofs + k0 + kk] = f2bf(tile[kk][nn]);
    }
}

// ================= Wv -> bf16 [256][448] (K-pad) =================
__global__ __launch_bounds__(256)
void wvbcast_kernel(const float* __restrict__ Wv, u16* __restrict__ wvb)
{
    int id = blockIdx.x * 256 + threadIdx.x;
    if (id >= 256 * KXP) return;
    int j = id / KXP, k = id % KXP;
    wvb[id] = (k < IVS) ? f2bf(Wv[(long)j * IVS + k]) : (u16)0;
}

// ================= t[r] = sum_k wgx[r][k] * bv[k]  (wave per row) ==========
__global__ __launch_bounds__(256)
void tvec_kernel(const u16* __restrict__ wgx, const float* __restrict__ bv,
                 float* __restrict__ tvec)
{
    const int wid  = threadIdx.x >> 6, lane = threadIdx.x & 63;
    const int r    = blockIdx.x * 4 + wid;
    if (r >= NU * NROWS3) return;
    const int k = lane * 8;
    float s = 0;
    if (k < IVS) {   // lanes 0..49 (400/8=50); wgx zero-padded beyond anyway
        short8 v = *(const short8*)&wgx[(long)r * KXP + k];
        #pragma unroll
        for (int i = 0; i < 8; i++) s = fmaf(bf2f((u16)v[i]), bv[k + i], s);
    }
    #pragma unroll
    for (int off = 32; off > 0; off >>= 1) s += __shfl_down(s, off);
    if (lane == 0) tvec[r] = s;
}

// ============ G2: qry = hs @ Wq (z=0..5) | k0 = x @ Wk + bk (z=6) ===========
__global__ __launch_bounds__(256)
void gemm_qry_kernel(const float* __restrict__ A,      // hs
                     const float* __restrict__ W,      // Wq
                     const float* __restrict__ x,
                     const float* __restrict__ Wk,
                     const float* __restrict__ bk,
                     float* __restrict__ C,            // qry
                     float* __restrict__ kv)           // k0
{
    const int u  = blockIdx.z;
    const int m0 = blockIdx.x * 64;
    const int tid = threadIdx.x;
    const int tm = tid / 16, tn = tid % 16;
    constexpr int N = IKS;    // 64

    const bool isk0 = (u == NU);
    const int  K   = isk0 ? NIN : NH;
    const long lda = isk0 ? NIN : (long)NU * NH;
    const float* Au = isk0 ? x : (A + (long)u * NH);
    const float* Wu = isk0 ? Wk : (W + (long)u * NH * N);

    __shared__ __align__(16) float As[32][72];
    __shared__ __align__(16) float Ws[32][68];
    float acc[4][4] = {};

    for (int k0 = 0; k0 < K; k0 += 32) {
        #pragma unroll
        for (int s2 = 0; s2 < 2; s2++) {
            int s = tid * 2 + s2;
            int row = s >> 3, kc = s & 7;
            float4 v = {0,0,0,0};
            if (k0 + kc*4 < K)
                v = *(const float4*)&Au[(long)(m0 + row) * lda + k0 + kc * 4];
            As[kc*4+0][row] = v.x; As[kc*4+1][row] = v.y;
            As[kc*4+2][row] = v.z; As[kc*4+3][row] = v.w;
        }
        #pragma unroll
        for (int s2 = 0; s2 < 2; s2++) {
            int s = tid * 2 + s2;
            int kr = s >> 4, c4 = s & 15;
            float4 v = {0,0,0,0};
            if (k0 + kr < K)
                v = *(const float4*)&Wu[(long)(k0 + kr) * N + c4 * 4];
            *(float4*)&Ws[kr][c4*4] = v;
        }
        __syncthreads();
        #pragma unroll
        for (int kk = 0; kk < 32; kk++) {
            float4 a4 = *(const float4*)&As[kk][tm*4];
            float4 w4 = *(const float4*)&Ws[kk][tn*4];
            float av[4] = {a4.x,a4.y,a4.z,a4.w}, wv[4] = {w4.x,w4.y,w4.z,w4.w};
            #pragma unroll
            for (int i = 0; i < 4; i++)
                #pragma unroll
                for (int j = 0; j < 4; j++)
                    acc[i][j] = fmaf(av[i], wv[j], acc[i][j]);
        }
        __syncthreads();
    }
    #pragma unroll
    for (int i = 0; i < 4; i++) {
        int row = m0 + tm*4 + i;
        #pragma unroll
        for (int j = 0; j < 4; j++) {
            int c = tn*4 + j;
            if (isk0) kv[(long)row*N + c] = acc[i][j] + bk[c];
            else      C[(long)row*(NU*IKS) + (long)u*IKS + c] = acc[i][j];
        }
    }
}

// ================= K3: scores / top-k mask =================
__global__ __launch_bounds__(64)
void score_kernel(const float* __restrict__ qry, const float* __restrict__ kv,
                  const float* __restrict__ bk,
                  float* __restrict__ c0, float* __restrict__ c1,
                  float* __restrict__ maskf)
{
    const int b = blockIdx.x;
    const int t = threadIdx.x;
    __shared__ float s0s[NU], s1s[NU];

    float k0v = kv[(long)b*IKS + t];
    float bkv = bk[t];
    for (int u = 0; u < NU; u++) {
        float q  = qry[((long)b*NU + u)*IKS + t];
        float p0 = q * k0v, p1 = q * bkv;
        #pragma unroll
        for (int off = 32; off > 0; off >>= 1) {
            p0 += __shfl_down(p0, off);
            p1 += __shfl_down(p1, off);
        }
        if (t == 0) { s0s[u] = p0 * 0.125f; s1s[u] = p1 * 0.125f; }
    }
    __syncthreads();
    if (t < NU) {
        int u = t;
        float su = s0s[u];
        int rank = 0;
        #pragma unroll
        for (int j = 0; j < NU; j++) {
            float sj = s0s[j];
            if (sj > su || (sj == su && j < u)) rank++;
        }
        float m = (rank < KTOP) ? 1.0f : 0.0f;
        float a = s0s[u], bb = s1s[u];
        float mx = fmaxf(a, bb);
        float e0 = expf(a - mx), e1 = expf(bb - mx);
        float p0 = e0 / (e0 + e1);
        c0[(long)b*NU + u]    = m * p0;
        c1[(long)b*NU + u]    = m * (1.0f - p0);
        maskf[(long)b*NU + u] = m;
    }
}

// ================= prep A for GRU GEMM: [c0*x | hs | 0] bf16 ================
__global__ __launch_bounds__(256)
void prep_gruA_kernel(const float* __restrict__ x, const float* __restrict__ hs,
                      const float* __restrict__ c0, u16* __restrict__ Ag)
{
    long id = (long)blockIdx.x * 256 + threadIdx.x;
    const long total = (long)NU * NB * (KG2 / 8);
    if (id >= total) return;
    int k8 = (int)(id % (KG2 / 8));
    int b  = (int)((id / (KG2 / 8)) % NB);
    int u  = (int)(id / ((long)(KG2 / 8) * NB));
    int k  = k8 * 8;
    u16 o[8];
    if (k < HOFS2) {
        float cv0 = c0[(long)b*NU + u];
        const float* xp = x + (long)b*NIN + k;
        #pragma unroll
        for (int i = 0; i < 8; i++) o[i] = f2bf(cv0 * xp[i]);
    } else if (k < HOFS2 + NH) {
        const float* hp = hs + ((long)b*NU + u)*NH + (k - HOFS2);
        #pragma unroll
        for (int i = 0; i < 8; i++) o[i] = f2bf(hp[i]);
    } else {
        #pragma unroll
        for (int i = 0; i < 8; i++) o[i] = 0;
    }
    *(short8*)&Ag[id * 8] = *(const short8*)o;
}

// ================= GRU MFMA (3 gates; K=896; BK=32, 3-buf, depth-1) =========
__global__ __launch_bounds__(256, 3)
void gru_mfma_kernel(const u16* __restrict__ Ag, const u16* __restrict__ Wg,
                     const float* __restrict__ tvec, const float* __restrict__ maskf,
                     const float* __restrict__ hs, u16* __restrict__ hnbf)
{
    const int u  = blockIdx.z;
    const int m0 = blockIdx.x * 128;
    const int n0 = blockIdx.y * 32;
    const int tid = threadIdx.x;
    const int wid = tid >> 6, lane = tid & 63;
    const int wm = wid >> 1, wn = wid & 1;
    const int lrow = lane & 15, lkq = lane >> 4;
    const int srow = lane >> 2;                               // 0..15
    const int scs  = (((lane & 3) ^ ((lane >> 3) & 3)) * 8);  // swizzled src chunk
    const int cofs = ((lkq ^ ((lrow >> 1) & 3)) * 8);         // read-side key

    __shared__ __align__(16) u16 As[3][128 * 32];
    __shared__ __align__(16) u16 Bs[3][128 * 32];

    const u16* Au = Ag + (long)u * NB * KG2;
    const u16* Wu = Wg + (long)u * NROWS3 * KG2;

    f32x4 aR[4], aI[4], aNX[4], aNH[4];
    #pragma unroll
    for (int m = 0; m < 4; m++) {
        aR[m] = (f32x4){0,0,0,0}; aI[m] = (f32x4){0,0,0,0};
        aNX[m] = (f32x4){0,0,0,0}; aNH[m] = (f32x4){0,0,0,0};
    }

#define GSTAGE(BUF, T) do {                                                   \
        const long kk0 = (long)(T) * 32;                                      \
        _Pragma("unroll")                                                     \
        for (int i2 = 0; i2 < 2; i2++) {                                      \
            int R = wid*32 + i2*16;                                           \
            int row = R + srow;                                               \
            gl_lds16(Au + (long)(m0 + row)*KG2 + kk0 + scs,                   \
                     &As[BUF][R * 32]);                                       \
            int g = row >> 5; if (g > 2) g = 2;  /* pad rows: L2-hot dup */   \
            int rn = row & 31;                                                \
            gl_lds16(Wu + ((long)g*NGATE + n0 + rn)*KG2 + kk0 + scs,          \
                     &Bs[BUF][R * 32]);                                       \
        }                                                                     \
    } while (0)

#define GCOMPUTE(BUF, T) do {                                                 \
        __builtin_amdgcn_s_setprio(1);                                        \
        short8 af[4], bR, bI, bN;                                             \
        _Pragma("unroll")                                                     \
        for (int m = 0; m < 4; m++)                                           \
            af[m] = *(const short8*)&As[BUF][(wm*64 + m*16 + lrow)*32 + cofs];\
        {                                                                     \
            int nr = wn*16 + lrow;                                            \
            bR = *(const short8*)&Bs[BUF][(0*32 + nr)*32 + cofs];             \
            bI = *(const short8*)&Bs[BUF][(1*32 + nr)*32 + cofs];             \
            bN = *(const short8*)&Bs[BUF][(2*32 + nr)*32 + cofs];             \
        }                                                                     \
        _Pragma("unroll")                                                     \
        for (int m = 0; m < 4; m++) {                                         \
            aR[m] = __builtin_amdgcn_mfma_f32_16x16x32_bf16(af[m], bR, aR[m], 0, 0, 0); \
            aI[m] = __builtin_amdgcn_mfma_f32_16x16x32_bf16(af[m], bI, aI[m], 0, 0, 0); \
        }                                                                     \
        if ((T) < HOFS2/32) {                                                 \
            _Pragma("unroll")                                                 \
            for (int m = 0; m < 4; m++)                                       \
                aNX[m] = __builtin_amdgcn_mfma_f32_16x16x32_bf16(af[m], bN, aNX[m], 0, 0, 0); \
        } else {                                                              \
            _Pragma("unroll")                                                 \
            for (int m = 0; m < 4; m++)                                       \
                aNH[m] = __builtin_amdgcn_mfma_f32_16x16x32_bf16(af[m], bN, aNH[m], 0, 0, 0); \
        }                                                                     \
        __builtin_amdgcn_s_setprio(0);                                        \
    } while (0)

    constexpr int KSTEPS = KG2 / 32;   // 28
    GSTAGE(0, 0);
    int bc = 0, bn = 1;
    for (int t = 0; t < KSTEPS - 1; ++t) {
        GSTAGE(bn, t + 1);
        WAITVM(4); SBAR();
        GCOMPUTE(bc, t);
        bc = bn; bn = (bn == 2) ? 0 : bn + 1;
    }
    WAITVM(0); SBAR();
    GCOMPUTE(bc, KSTEPS - 1);
#undef GCOMPUTE
#undef GSTAGE

    const int col = n0 + wn*16 + lrow;
    float tR = 0, tI = 0, tN = 0;
    if (col < NH) {
        tR = tvec[(long)u*NROWS3 + col];
        tI = tvec[(long)u*NROWS3 + NGATE + col];
        tN = tvec[(long)u*NROWS3 + 2*NGATE + col];
    }
    #pragma unroll
    for (int m = 0; m < 4; m++) {
        #pragma unroll
        for (int r = 0; r < 4; r++) {
            int row = m0 + wm*64 + m*16 + lkq*4 + r;   // b
            u16 ov = 0;
            if (col < NH) {
                float mk = maskf[(long)row*NU + u];
                float rg = 1.0f / (1.0f + expf(-(aR[m][r] + mk*tR)));
                float ig = 1.0f / (1.0f + expf(-(aI[m][r] + mk*tI)));
                float ng = tanhf(aNX[m][r] + mk*tN + rg * aNH[m][r]);
                float h  = hs[((long)row*NU + u)*NH + col];
                ov = f2bf(ng + ig * (h - ng));
            }
            hnbf[(long)u*NB*KH + (long)row*KH + col] = ov;
        }
    }
}

// ================= generic 128x128 bf16 MFMA GEMM (BK=64, 2-buf counted) ====
// EPI=0: f32 store; EPI=1: final out blend; EPI=2: bf16 store
template<int EPI>
__global__ __launch_bounds__(256, 2)
void mfgemm_kernel(const u16* __restrict__ A, long sAu, int lda,
                   const u16* __restrict__ Bw, long sBu, int ldb,
                   float* __restrict__ Cf, u16* __restrict__ C16,
                   long sCu, int ldc, int ksteps,      // ksteps in BK=64 units
                   const float* __restrict__ maskf,
                   const u16* __restrict__ hnbf,
                   const float* __restrict__ hs,
                   int bbase)
{
    const int u  = blockIdx.z;
    const int m0 = blockIdx.x * 128;
    const int n0 = blockIdx.y * 128;
    const int tid = threadIdx.x;
    const int wid = tid >> 6, lane = tid & 63;
    const int wm = wid >> 1, wn = wid & 1;
    const int lrow = lane & 15, lkq = lane >> 4;
    const int l8 = lane & 7, lr8 = lane >> 3;
    const int rsw = lrow & 7;

    __shared__ __align__(16) u16 As[2][128 * 64];
    __shared__ __align__(16) u16 Bs[2][128 * 64];

    const u16* Au = A + (long)u * sAu;
    const u16* Bu = Bw + (long)u * sBu;

    f32x4 acc[4][4];
    #pragma unroll
    for (int m = 0; m < 4; m++)
        #pragma unroll
        for (int n = 0; n < 4; n++) acc[m][n] = (f32x4){0,0,0,0};

#define MSTAGE(BUF, KS) do {                                                  \
        const long kk0 = (long)(KS) * 64;                                     \
        _Pragma("unroll")                                                     \
        for (int i2 = 0; i2 < 4; i2++) {                                      \
            int rw = i2*32 + wid*8 + lr8;                                     \
            int co = ((l8 ^ (rw & 7)) * 8);                                   \
            gl_lds16(Au + (long)(m0 + rw)*lda + kk0 + co,                     \
                     &As[BUF][(i2*32 + wid*8) * 64]);                         \
            gl_lds16(Bu + (long)(n0 + rw)*ldb + kk0 + co,                     \
                     &Bs[BUF][(i2*32 + wid*8) * 64]);                         \
        }                                                                     \
    } while (0)

#define MCOMPUTE(BUF) do {                                                    \
        __builtin_amdgcn_s_setprio(1);                                        \
        _Pragma("unroll")                                                     \
        for (int ks2 = 0; ks2 < 2; ks2++) {                                   \
            const int cofs = (((ks2*4 + lkq) ^ rsw) * 8);                     \
            short8 af[4], bfr[4];                                             \
            _Pragma("unroll")                                                 \
            for (int m = 0; m < 4; m++)                                       \
                af[m] = *(const short8*)&As[BUF][(wm*64 + m*16 + lrow)*64 + cofs]; \
            _Pragma("unroll")                                                 \
            for (int n = 0; n < 4; n++)                                       \
                bfr[n] = *(const short8*)&Bs[BUF][(wn*64 + n*16 + lrow)*64 + cofs]; \
            _Pragma("unroll")                                                 \
            for (int m = 0; m < 4; m++)                                       \
                _Pragma("unroll")                                             \
                for (int n = 0; n < 4; n++)                                   \
                    acc[m][n] = __builtin_amdgcn_mfma_f32_16x16x32_bf16(af[m], bfr[n], acc[m][n], 0, 0, 0); \
        }                                                                     \
        __builtin_amdgcn_s_setprio(0);                                        \
    } while (0)

#define MPH(BUF, T, W) do {                                                   \
        if ((T) + 1 < ksteps) MSTAGE((BUF)^1, (T)+1);                         \
        WAITVM(W); SBAR();                                                    \
        MCOMPUTE(BUF);                                                        \
        WAITLG(); SBAR();                                                     \
    } while (0)

    MSTAGE(0, 0);
    int t = 0;
    for (; t + 2 < ksteps; t += 2) { MPH(0, t, 8); MPH(1, t+1, 8); }
    if (t + 2 == ksteps) { MPH(0, t, 8); MPH(1, t+1, 0); }
    else                 { MPH(0, t, 0); }   // odd tail (used by M-GEMM, ksteps=7)
#undef MPH
#undef MCOMPUTE
#undef MSTAGE

    #pragma unroll
    for (int m = 0; m < 4; m++) {
        #pragma unroll
        for (int r = 0; r < 4; r++) {
            int row = m0 + wm*64 + m*16 + lkq*4 + r;
            #pragma unroll
            for (int n = 0; n < 4; n++) {
                int col = n0 + wn*64 + n*16 + lrow;
                float v = acc[m][n][r];
                if (EPI == 0) {
                    Cf[(long)u*sCu + (long)row*ldc + col] = v;
                } else if (EPI == 2) {
                    C16[(long)u*sCu + (long)row*ldc + col] = f2bf(v);
                } else {
                    if (col < NH) {
                        int b = bbase + row;
                        long o = ((long)b*NU + u)*NH + col;
                        float mk = maskf[(long)b*NU + u];
                        float hv = bf2f(hnbf[(long)u*NB*KH + (long)b*KH + col]);
                        Cf[o] = (mk > 0.5f) ? (v + hv) : hs[o];
                    }
                }
            }
        }
    }
}

// ================= K7: attention weights (one block per b) =================
__global__ __launch_bounds__(256)
void attw_kernel(const float* __restrict__ qk, const float* __restrict__ maskf,
                 float* __restrict__ attw)
{
    const int b = blockIdx.x;
    const int t = threadIdx.x;
    __shared__ float qks[NU * QKW];              // 6KB
    __shared__ float lg[NCH][NU][NU];

    for (int i = t; i < NU * QKW / 4; i += 256)
        *(float4*)&qks[i * 4] = *(const float4*)&qk[(long)b * NU * QKW + i * 4];
    __syncthreads();

    if (t < NCH * NU * NU) {
        int h = t / 36, uq = (t % 36) / 6, un = t % 6;
        const float* qp = &qks[uq * QKW + h * 32];
        const float* kp = &qks[un * QKW + 128 + h * 32];
        float s = 0;
        #pragma unroll
        for (int i = 0; i < 32; i++) s = fmaf(qp[i], kp[i], s);
        lg[h][uq][un] = s * 0.17677669529663687f;
    }
    __syncthreads();
    if (t < NCH * NU) {
        int h = t / NU, uq = t % NU;
        float mx = -1e30f;
        #pragma unroll
        for (int n = 0; n < NU; n++) mx = fmaxf(mx, lg[h][uq][n]);
        float e[NU], se = 0;
        #pragma unroll
        for (int n = 0; n < NU; n++) { e[n] = expf(lg[h][uq][n] - mx); se += e[n]; }
        float m = maskf[(long)b*NU + uq];
        float inv = m / se;
        #pragma unroll
        for (int n = 0; n < NU; n++)
            attw[(((long)b*NCH + h)*NU + uq)*NU + n] = e[n] * inv;
    }
}

// ================= ctx = att @ v, IN-PLACE on the v buffer ==================
__global__ __launch_bounds__(256)
void ctx2_kernel(const float* __restrict__ attw, u16* vc, int bbase)
{
    __shared__ float att_s[32][NCH * NU * NU];   // [bl][h*36+u*6+n] = 144
    const int c0 = blockIdx.x * 64;
    const int b0 = blockIdx.y * 32;
    const int tid = threadIdx.x;

    for (int i = tid; i < 32 * 144; i += 256) {
        int bl = i / 144, j = i % 144;
        att_s[bl][j] = attw[(long)(bbase + b0 + bl) * 144 + j];
    }
    __syncthreads();

    const int bl = tid >> 3;
    const int c  = c0 + (tid & 7) * 8;
    const long rowbase = (long)(b0 + bl) * NU;   // chunk-local

    if (c >= VW) {   // pad columns -> zero
        short8 z = {0,0,0,0,0,0,0,0};
        #pragma unroll
        for (int u = 0; u < NU; u++)
            *(short8*)&vc[(rowbase + u) * VN + c] = z;
        return;
    }
    const int h = c / CVS;
    const float* aw = &att_s[bl][h * 36];

    float vf[NU][8];
    #pragma unroll
    for (int n = 0; n < NU; n++) {
        short8 vv = *(const short8*)&vc[(rowbase + n) * VN + c];
        #pragma unroll
        for (int i = 0; i < 8; i++) vf[n][i] = bf2f((u16)vv[i]);
    }
    #pragma unroll
    for (int u = 0; u < NU; u++) {
        float acc[8] = {};
        #pragma unroll
        for (int n = 0; n < NU; n++) {
            float a = aw[u * 6 + n];
            #pragma unroll
            for (int i = 0; i < 8; i++) acc[i] = fmaf(a, vf[n][i], acc[i]);
        }
        short8 o;
        #pragma unroll
        for (int i = 0; i < 8; i++) o[i] = (short)f2bf(acc[i]);
        *(short8*)&vc[(rowbase + u) * VN + c] = o;
    }
}

// ================= host launcher =================
extern "C" void kernel_launch(void* const* d_in, const int* in_sizes, int n_in,
                              void* d_out, int out_size, void* d_ws, size_t ws_size,
                              hipStream_t stream)
{
    const float* x    = (const float*)d_in[0];
    const float* hs   = (const float*)d_in[1];
    const float* Wk   = (const float*)d_in[2];
    const float* bk   = (const float*)d_in[3];
    const float* Wv   = (const float*)d_in[4];
    const float* bv   = (const float*)d_in[5];
    const float* Wq   = (const float*)d_in[6];
    const float* x2h  = (const float*)d_in[7];
    const float* h2h  = (const float*)d_in[8];
    const float* Wq_  = (const float*)d_in[9];
    const float* Wk_  = (const float*)d_in[10];
    const float* Wv_  = (const float*)d_in[11];
    const float* Wout = (const float*)d_in[12];
    float* out = (float*)d_out;
    float* ws  = (float*)d_ws;

    float* kv    = ws + OFF_KV;
    float* qry   = ws + OFF_QRY;
    float* c0b   = ws + OFF_C0;
    float* c1b   = ws + OFF_C1;
    float* maskf = ws + OFF_MASK;
    float* qk    = ws + OFF_QK;
    float* attw  = ws + OFF_ATTW;
    u16*   hnbf  = (u16*)(ws + OFF_HNBF);
    u16*   wqk   = (u16*)(ws + OFF_WQK);
    u16*   wv    = (u16*)(ws + OFF_WV);
    u16*   wout  = (u16*)(ws + OFF_WOUT);
    u16*   wvb   = (u16*)(ws + OFF_WVB);
    float* tvec  = ws + OFF_TVEC;
    u16*   wgru2 = (u16*)(ws + OFF_WGRU2);
    u16*   agru2 = (u16*)(ws + OFF_AGRU2);
    u16*   wgx   = (u16*)(ws + OFF_WGRUX);  // aliased with agru2 (dead first)
    u16*   vcbuf = (u16*)(ws + OFF_VBUF);   // aliases wgru2+agru2 (chunk phase)

    // 1) weight conversions/transposes (k-pads zero-written by wtrans)
    wtrans_kernel<<<dim3(20, 4, NU), 256, 0, stream>>>(
        Wq_, (long)NH*128, 128, 0, NH, 128, wqk, (long)QKW*KH, KH, 0, 0, 1, 0, 0);
    wtrans_kernel<<<dim3(20, 4, NU), 256, 0, stream>>>(
        Wk_, (long)NH*128, 128, 0, NH, 128, wqk, (long)QKW*KH, KH, 128, 0, 1, 0, 0);
    wtrans_kernel<<<dim3(20, 75, NU), 256, 0, stream>>>(
        Wv_, (long)NH*VW, VW, 0, NH, VW, wv, (long)VN*KH, KH, 0, 0, 1, 0, 0);
    wtrans_kernel<<<dim3(76, 19, NU), 256, 0, stream>>>(
        Wout, (long)VW*NH, NH, 0, VW, NH, wout, (long)NGATE*VN, VN, 0, 0, 1, 0, 0);
    // x2h^T -> wgx [NU][1920][448]  (g folded into grid.z)
    wtrans_kernel<<<dim3(KXP/32, 19, NU*3), 256, 0, stream>>>(
        x2h, (long)IVS*3*NH, 3*NH, 0, IVS, NH,
        wgx, (long)NROWS3*KXP, KXP, 0, 0, 3, NH, NGATE);
    // h2h^T -> wgru2 k 256..895
    wtrans_kernel<<<dim3(20, 19, NU*3), 256, 0, stream>>>(
        h2h, (long)NH*3*NH, 3*NH, 0, NH, NH,
        wgru2, (long)NROWS3*KG2, KG2, 0, HOFS2, 3, NH, NGATE);
    // Wv -> bf16 [256][448]
    wvbcast_kernel<<<(256*KXP + 255)/256, 256, 0, stream>>>(Wv, wvb);
    // M^T[u] = x2h^T @ Wv : wgru2 k 0..255   (ksteps = 7, odd tail)
    mfgemm_kernel<2><<<dim3(NROWS3/128, 2, NU), 256, 0, stream>>>(
        wgx, (long)NROWS3*KXP, KXP, wvb, 0L, KXP,
        nullptr, wgru2, (long)NROWS3*KG2, KG2, KXP/64, nullptr, nullptr, nullptr, 0);
    // t[u] = x2h^T @ bv  (wave per row)
    tvec_kernel<<<(NU*NROWS3 + 3)/4, 256, 0, stream>>>(wgx, bv, tvec);

    // 2) f32 front-end: qry (z=0..5) + k0 (z=6) fused
    gemm_qry_kernel<<<dim3(NB/64, 1, NU + 1), 256, 0, stream>>>(
        hs, Wq, x, Wk, bk, qry, kv);
    score_kernel<<<NB, 64, 0, stream>>>(qry, kv, bk, c0b, c1b, maskf);

    // 3) GRU A prep (AFTER M-GEMM+tvec: agru2 overwrites wgx) + GRU MFMA
    {
        long total = (long)NU * NB * (KG2/8);
        prep_gruA_kernel<<<(unsigned)((total + 255)/256), 256, 0, stream>>>(
            x, hs, c0b, agru2);
    }
    gru_mfma_kernel<<<dim3(NB/128, NGATE/32, NU), 256, 0, stream>>>(
        agru2, wgru2, tvec, maskf, hs, hnbf);

    // 4) qk projection (MFMA) + attention weights
    mfgemm_kernel<0><<<dim3(NB/128, QKW/128, NU), 256, 0, stream>>>(
        hnbf, (long)NB*KH, KH, wqk, (long)QKW*KH, KH,
        qk, nullptr, (long)QKW, NU*QKW, KH/64, nullptr, nullptr, nullptr, 0);
    attw_kernel<<<NB, 256, 0, stream>>>(qk, maskf, attw);

    // 5) chunked v / ctx(in-place) / out  (BC=2048, 2 chunks)
    for (int ch = 0; ch < NCHUNK; ch++) {
        mfgemm_kernel<2><<<dim3(BC/128, VN/128, NU), 256, 0, stream>>>(
            hnbf + (long)ch*BC*KH, (long)NB*KH, KH, wv, (long)VN*KH, KH,
            nullptr, vcbuf, (long)VN, NU*VN, KH/64, nullptr, nullptr, nullptr, 0);
        ctx2_kernel<<<dim3(VN/64, BC/32), 256, 0, stream>>>(
            attw, vcbuf, ch*BC);
        mfgemm_kernel<1><<<dim3(BC/128, NGATE/128, NU), 256, 0, stream>>>(
            vcbuf, (long)VN, NU*VN, wout, (long)NGATE*VN, VN,
            out, nullptr, 0, 0, VN/64, maskf, hnbf, hs, ch*BC);
    }
}

// Round 16
// 679.281 us; speedup vs baseline: 1.1008x; 1.0045x over previous
//
#include <hip/hip_runtime.h>
#include <math.h>

typedef unsigned short u16;
typedef __attribute__((ext_vector_type(8))) short short8;
typedef __attribute__((ext_vector_type(4))) float f32x4;

// ---------------- problem constants ----------------
constexpr int NB   = 4096;   // B
constexpr int NU   = 6;      // U
constexpr int NIN  = 256;    // IN
constexpr int NH   = 600;    // H
constexpr int IKS  = 64;
constexpr int IVS  = 400;
constexpr int NCH  = 4;
constexpr int CVS  = 600;
constexpr int KTOP = 4;

constexpr int QKW  = 256;            // q(128)|k(128)
constexpr int VW   = NCH * CVS;      // 2400

// padded MFMA dims
constexpr int KG2   = 896;           // GRU K: [c0*x (256) | hs (600) | pad]
constexpr int HOFS2 = 256;           // hs starts here (8*32)
constexpr int NGATE = 640;           // 600 padded
constexpr int NROWS3= 3 * NGATE;     // 1920
constexpr int KXP   = 448;           // x2h k-pad (400 -> 7*64)
constexpr int KH    = 640;           // hnew K padded
constexpr int VN    = 2432;          // 2400 padded (19*128)
constexpr int BC    = 2048;          // chunk rows (in-place ctx)
constexpr int NCHUNK = NB / BC;      // 2

// ---------------- ws layout (float offsets) ----------------
constexpr long OFF_KV   = 0;                                   // f32 [NB][64] (k0)
constexpr long OFF_QRY  = OFF_KV   + (long)NB * IKS;           // f32 [NB][NU][64]
constexpr long OFF_C0   = OFF_QRY  + (long)NB * NU * IKS;
constexpr long OFF_C1   = OFF_C0   + (long)NB * NU;
constexpr long OFF_MASK = OFF_C1   + (long)NB * NU;
constexpr long OFF_QK   = OFF_MASK + (long)NB * NU;            // f32 [NB][NU][256]
constexpr long OFF_ATTW = OFF_QK   + (long)NB * NU * QKW;      // f32 [NB][NCH][NU][NU]
constexpr long OFF_HNBF = OFF_ATTW + (long)NB * NCH * NU * NU; // bf16 [NU][NB][640]
constexpr long OFF_WQK  = OFF_HNBF + (long)NU * NB * KH / 2;   // bf16 [NU][256][640]
constexpr long OFF_WV   = OFF_WQK  + (long)NU * QKW * KH / 2;  // bf16 [NU][2432][640]
constexpr long OFF_WOUT = OFF_WV   + (long)NU * VN * KH / 2;   // bf16 [NU][640][2432]
constexpr long OFF_WVB  = OFF_WOUT + (long)NU * NGATE * VN / 2;// bf16 [256][448]
constexpr long OFF_TVEC = OFF_WVB  + (long)256 * KXP / 2;      // f32 [NU][1920]
constexpr long OFF_WGRU2= OFF_TVEC + (long)NU * NROWS3;        // bf16 [NU][1920][896]
constexpr long OFF_AGRU2= OFF_WGRU2+ (long)NU * NROWS3 * KG2/2;// bf16 [NU][NB][896]
// aliases: wgru_x (bf16 [NU][1920][448]) lives in AGRU2 space (dead before prep
// writes agru2); VBUF (bf16 [BC][NU][VN]) aliases WGRU2+AGRU2 (dead after gru).
constexpr long OFF_WGRUX = OFF_AGRU2;
constexpr long OFF_VBUF  = OFF_WGRU2;

// ---------------- helpers ----------------
__device__ __forceinline__ u16 f2bf(float f) {
    unsigned int x = __float_as_uint(f);
    x += 0x7FFFu + ((x >> 16) & 1u);
    return (u16)(x >> 16);
}
__device__ __forceinline__ float bf2f(u16 u) {
    return __uint_as_float(((unsigned int)u) << 16);
}
__device__ __forceinline__ void gl_lds16(const u16* g, u16* l) {
    __builtin_amdgcn_global_load_lds(
        (const __attribute__((address_space(1))) void*)g,
        (__attribute__((address_space(3))) void*)l, 16, 0, 0);
}

// counted-wait / barrier primitives (never drain vmcnt to 0 mid-loop)
#define WAITVM_(N) asm volatile("s_waitcnt vmcnt(" #N ")" ::: "memory")
#define WAITVM(N)  WAITVM_(N)
#define WAITLG()   asm volatile("s_waitcnt lgkmcnt(0)" ::: "memory")
#define SBAR()     do { __builtin_amdgcn_sched_barrier(0); \
                        __builtin_amdgcn_s_barrier();      \
                        __builtin_amdgcn_sched_barrier(0); } while (0)

// ================= weight transpose f32[K][N] -> bf16[n][k] =================
// gdiv>1 with src2==nullptr: g selects source column group (x2h/h2h gates).
// gdiv==2 with src2!=nullptr: g selects SOURCE POINTER (Wq_/Wk_ fusion).
__global__ __launch_bounds__(256)
void wtrans_kernel(const float* __restrict__ src, const float* __restrict__ src2,
                   long s_u, int s_ld, int s_colofs,
                   int Ksrc, int Nsub,
                   u16* __restrict__ dst, long d_u, int d_ld, int d_nofs, int d_kofs,
                   int gdiv, int s_gcol, int d_gnofs)
{
    __shared__ float tile[32][33];
    int z = blockIdx.z;
    int u = z, g = 0;
    if (gdiv > 1) { u = z / gdiv; g = z % gdiv; }
    const int k0 = blockIdx.x * 32, n0 = blockIdx.y * 32;
    const int t  = threadIdx.x;
    const float* Sb = (src2 && g) ? src2 : src;
    const int scol = s_colofs + (src2 ? 0 : g * s_gcol);
    const int dnof = d_nofs + g * d_gnofs;
    const float* S = Sb + (long)u * s_u;
    u16* D = dst + (long)u * d_u;
    #pragma unroll
    for (int r = 0; r < 4; r++) {
        int kk = r * 8 + (t >> 5), nn = t & 31;
        float v = 0.f;
        if (k0 + kk < Ksrc && n0 + nn < Nsub)
            v = S[(long)(k0 + kk) * s_ld + scol + n0 + nn];
        tile[kk][nn] = v;
    }
    __syncthreads();
    #pragma unroll
    for (int r = 0; r < 4; r++) {
        int nn = r * 8 + (t >> 5), kk = t & 31;
        if (n0 + nn < Nsub)
            D[(long)(dnof + n0 + nn) * d_ld + d_kofs + k0 + kk] = f2bf(tile[kk][nn]);
    }
}

// ===== fused: t[r] = wgx[r]·bv (wave/row)  +  Wv -> bf16 [256][448] tail ====
constexpr int TVEC_BLKS = (NU * NROWS3 + 3) / 4;          // 2880
constexpr int WVB_BLKS  = (256 * KXP + 255) / 256;        // 448
__global__ __launch_bounds__(256)
void tvec_wvb_kernel(const u16* __restrict__ wgx, const float* __restrict__ bv,
                     float* __restrict__ tvec,
                     const float* __restrict__ Wv, u16* __restrict__ wvb)
{
    if ((int)blockIdx.x < TVEC_BLKS) {
        const int wid  = threadIdx.x >> 6, lane = threadIdx.x & 63;
        const int r    = blockIdx.x * 4 + wid;
        if (r >= NU * NROWS3) return;
        const int k = lane * 8;
        float s = 0;
        if (k < IVS) {
            short8 v = *(const short8*)&wgx[(long)r * KXP + k];
            #pragma unroll
            for (int i = 0; i < 8; i++) s = fmaf(bf2f((u16)v[i]), bv[k + i], s);
        }
        #pragma unroll
        for (int off = 32; off > 0; off >>= 1) s += __shfl_down(s, off);
        if (lane == 0) tvec[r] = s;
    } else {
        int id = (blockIdx.x - TVEC_BLKS) * 256 + threadIdx.x;
        if (id >= 256 * KXP) return;
        int j = id / KXP, k = id % KXP;
        wvb[id] = (k < IVS) ? f2bf(Wv[(long)j * IVS + k]) : (u16)0;
    }
}

// ============ G2: qry = hs @ Wq (z=0..5) | k0 = x @ Wk + bk (z=6) ===========
__global__ __launch_bounds__(256)
void gemm_qry_kernel(const float* __restrict__ A,      // hs
                     const float* __restrict__ W,      // Wq
                     const float* __restrict__ x,
                     const float* __restrict__ Wk,
                     const float* __restrict__ bk,
                     float* __restrict__ C,            // qry
                     float* __restrict__ kv)           // k0
{
    const int u  = blockIdx.z;
    const int m0 = blockIdx.x * 64;
    const int tid = threadIdx.x;
    const int tm = tid / 16, tn = tid % 16;
    constexpr int N = IKS;    // 64

    const bool isk0 = (u == NU);
    const int  K   = isk0 ? NIN : NH;
    const long lda = isk0 ? NIN : (long)NU * NH;
    const float* Au = isk0 ? x : (A + (long)u * NH);
    const float* Wu = isk0 ? Wk : (W + (long)u * NH * N);

    __shared__ __align__(16) float As[32][72];
    __shared__ __align__(16) float Ws[32][68];
    float acc[4][4] = {};

    for (int k0 = 0; k0 < K; k0 += 32) {
        #pragma unroll
        for (int s2 = 0; s2 < 2; s2++) {
            int s = tid * 2 + s2;
            int row = s >> 3, kc = s & 7;
            float4 v = {0,0,0,0};
            if (k0 + kc*4 < K)
                v = *(const float4*)&Au[(long)(m0 + row) * lda + k0 + kc * 4];
            As[kc*4+0][row] = v.x; As[kc*4+1][row] = v.y;
            As[kc*4+2][row] = v.z; As[kc*4+3][row] = v.w;
        }
        #pragma unroll
        for (int s2 = 0; s2 < 2; s2++) {
            int s = tid * 2 + s2;
            int kr = s >> 4, c4 = s & 15;
            float4 v = {0,0,0,0};
            if (k0 + kr < K)
                v = *(const float4*)&Wu[(long)(k0 + kr) * N + c4 * 4];
            *(float4*)&Ws[kr][c4*4] = v;
        }
        __syncthreads();
        #pragma unroll
        for (int kk = 0; kk < 32; kk++) {
            float4 a4 = *(const float4*)&As[kk][tm*4];
            float4 w4 = *(const float4*)&Ws[kk][tn*4];
            float av[4] = {a4.x,a4.y,a4.z,a4.w}, wv[4] = {w4.x,w4.y,w4.z,w4.w};
            #pragma unroll
            for (int i = 0; i < 4; i++)
                #pragma unroll
                for (int j = 0; j < 4; j++)
                    acc[i][j] = fmaf(av[i], wv[j], acc[i][j]);
        }
        __syncthreads();
    }
    #pragma unroll
    for (int i = 0; i < 4; i++) {
        int row = m0 + tm*4 + i;
        #pragma unroll
        for (int j = 0; j < 4; j++) {
            int c = tn*4 + j;
            if (isk0) kv[(long)row*N + c] = acc[i][j] + bk[c];
            else      C[(long)row*(NU*IKS) + (long)u*IKS + c] = acc[i][j];
        }
    }
}

// ================= K3: scores / top-k mask =================
__global__ __launch_bounds__(64)
void score_kernel(const float* __restrict__ qry, const float* __restrict__ kv,
                  const float* __restrict__ bk,
                  float* __restrict__ c0, float* __restrict__ c1,
                  float* __restrict__ maskf)
{
    const int b = blockIdx.x;
    const int t = threadIdx.x;
    __shared__ float s0s[NU], s1s[NU];

    float k0v = kv[(long)b*IKS + t];
    float bkv = bk[t];
    for (int u = 0; u < NU; u++) {
        float q  = qry[((long)b*NU + u)*IKS + t];
        float p0 = q * k0v, p1 = q * bkv;
        #pragma unroll
        for (int off = 32; off > 0; off >>= 1) {
            p0 += __shfl_down(p0, off);
            p1 += __shfl_down(p1, off);
        }
        if (t == 0) { s0s[u] = p0 * 0.125f; s1s[u] = p1 * 0.125f; }
    }
    __syncthreads();
    if (t < NU) {
        int u = t;
        float su = s0s[u];
        int rank = 0;
        #pragma unroll
        for (int j = 0; j < NU; j++) {
            float sj = s0s[j];
            if (sj > su || (sj == su && j < u)) rank++;
        }
        float m = (rank < KTOP) ? 1.0f : 0.0f;
        float a = s0s[u], bb = s1s[u];
        float mx = fmaxf(a, bb);
        float e0 = expf(a - mx), e1 = expf(bb - mx);
        float p0 = e0 / (e0 + e1);
        c0[(long)b*NU + u]    = m * p0;
        c1[(long)b*NU + u]    = m * (1.0f - p0);
        maskf[(long)b*NU + u] = m;
    }
}

// ================= prep A for GRU GEMM: [c0*x | hs | 0] bf16 ================
__global__ __launch_bounds__(256)
void prep_gruA_kernel(const float* __restrict__ x, const float* __restrict__ hs,
                      const float* __restrict__ c0, u16* __restrict__ Ag)
{
    long id = (long)blockIdx.x * 256 + threadIdx.x;
    const long total = (long)NU * NB * (KG2 / 8);
    if (id >= total) return;
    int k8 = (int)(id % (KG2 / 8));
    int b  = (int)((id / (KG2 / 8)) % NB);
    int u  = (int)(id / ((long)(KG2 / 8) * NB));
    int k  = k8 * 8;
    u16 o[8];
    if (k < HOFS2) {
        float cv0 = c0[(long)b*NU + u];
        const float* xp = x + (long)b*NIN + k;
        #pragma unroll
        for (int i = 0; i < 8; i++) o[i] = f2bf(cv0 * xp[i]);
    } else if (k < HOFS2 + NH) {
        const float* hp = hs + ((long)b*NU + u)*NH + (k - HOFS2);
        #pragma unroll
        for (int i = 0; i < 8; i++) o[i] = f2bf(hp[i]);
    } else {
        #pragma unroll
        for (int i = 0; i < 8; i++) o[i] = 0;
    }
    *(short8*)&Ag[id * 8] = *(const short8*)o;
}

// ================= GRU MFMA (3 gates; K=896; BK=32, 3-buf, depth-1) =========
__global__ __launch_bounds__(256, 3)
void gru_mfma_kernel(const u16* __restrict__ Ag, const u16* __restrict__ Wg,
                     const float* __restrict__ tvec, const float* __restrict__ maskf,
                     const float* __restrict__ hs, u16* __restrict__ hnbf)
{
    const int u  = blockIdx.z;
    const int m0 = blockIdx.x * 128;
    const int n0 = blockIdx.y * 32;
    const int tid = threadIdx.x;
    const int wid = tid >> 6, lane = tid & 63;
    const int wm = wid >> 1, wn = wid & 1;
    const int lrow = lane & 15, lkq = lane >> 4;
    const int srow = lane >> 2;                               // 0..15
    const int scs  = (((lane & 3) ^ ((lane >> 3) & 3)) * 8);  // swizzled src chunk
    const int cofs = ((lkq ^ ((lrow >> 1) & 3)) * 8);         // read-side key

    __shared__ __align__(16) u16 As[3][128 * 32];
    __shared__ __align__(16) u16 Bs[3][128 * 32];

    const u16* Au = Ag + (long)u * NB * KG2;
    const u16* Wu = Wg + (long)u * NROWS3 * KG2;

    f32x4 aR[4], aI[4], aNX[4], aNH[4];
    #pragma unroll
    for (int m = 0; m < 4; m++) {
        aR[m] = (f32x4){0,0,0,0}; aI[m] = (f32x4){0,0,0,0};
        aNX[m] = (f32x4){0,0,0,0}; aNH[m] = (f32x4){0,0,0,0};
    }

#define GSTAGE(BUF, T) do {                                                   \
        const long kk0 = (long)(T) * 32;                                      \
        _Pragma("unroll")                                                     \
        for (int i2 = 0; i2 < 2; i2++) {                                      \
            int R = wid*32 + i2*16;                                           \
            int row = R + srow;                                               \
            gl_lds16(Au + (long)(m0 + row)*KG2 + kk0 + scs,                   \
                     &As[BUF][R * 32]);                                       \
            int g = row >> 5; if (g > 2) g = 2;  /* pad rows: L2-hot dup */   \
            int rn = row & 31;                                                \
            gl_lds16(Wu + ((long)g*NGATE + n0 + rn)*KG2 + kk0 + scs,          \
                     &Bs[BUF][R * 32]);                                       \
        }                                                                     \
    } while (0)

#define GCOMPUTE(BUF, T) do {                                                 \
        __builtin_amdgcn_s_setprio(1);                                        \
        short8 af[4], bR, bI, bN;                                             \
        _Pragma("unroll")                                                     \
        for (int m = 0; m < 4; m++)                                           \
            af[m] = *(const short8*)&As[BUF][(wm*64 + m*16 + lrow)*32 + cofs];\
        {                                                                     \
            int nr = wn*16 + lrow;                                            \
            bR = *(const short8*)&Bs[BUF][(0*32 + nr)*32 + cofs];             \
            bI = *(const short8*)&Bs[BUF][(1*32 + nr)*32 + cofs];             \
            bN = *(const short8*)&Bs[BUF][(2*32 + nr)*32 + cofs];             \
        }                                                                     \
        _Pragma("unroll")                                                     \
        for (int m = 0; m < 4; m++) {                                         \
            aR[m] = __builtin_amdgcn_mfma_f32_16x16x32_bf16(af[m], bR, aR[m], 0, 0, 0); \
            aI[m] = __builtin_amdgcn_mfma_f32_16x16x32_bf16(af[m], bI, aI[m], 0, 0, 0); \
        }                                                                     \
        if ((T) < HOFS2/32) {                                                 \
            _Pragma("unroll")                                                 \
            for (int m = 0; m < 4; m++)                                       \
                aNX[m] = __builtin_amdgcn_mfma_f32_16x16x32_bf16(af[m], bN, aNX[m], 0, 0, 0); \
        } else {                                                              \
            _Pragma("unroll")                                                 \
            for (int m = 0; m < 4; m++)                                       \
                aNH[m] = __builtin_amdgcn_mfma_f32_16x16x32_bf16(af[m], bN, aNH[m], 0, 0, 0); \
        }                                                                     \
        __builtin_amdgcn_s_setprio(0);                                        \
    } while (0)

    constexpr int KSTEPS = KG2 / 32;   // 28
    GSTAGE(0, 0);
    int bc = 0, bn = 1;
    for (int t = 0; t < KSTEPS - 1; ++t) {
        GSTAGE(bn, t + 1);
        WAITVM(4); SBAR();
        GCOMPUTE(bc, t);
        bc = bn; bn = (bn == 2) ? 0 : bn + 1;
    }
    WAITVM(0); SBAR();
    GCOMPUTE(bc, KSTEPS - 1);
#undef GCOMPUTE
#undef GSTAGE

    const int col = n0 + wn*16 + lrow;
    float tR = 0, tI = 0, tN = 0;
    if (col < NH) {
        tR = tvec[(long)u*NROWS3 + col];
        tI = tvec[(long)u*NROWS3 + NGATE + col];
        tN = tvec[(long)u*NROWS3 + 2*NGATE + col];
    }
    #pragma unroll
    for (int m = 0; m < 4; m++) {
        #pragma unroll
        for (int r = 0; r < 4; r++) {
            int row = m0 + wm*64 + m*16 + lkq*4 + r;   // b
            u16 ov = 0;
            if (col < NH) {
                float mk = maskf[(long)row*NU + u];
                float rg = 1.0f / (1.0f + expf(-(aR[m][r] + mk*tR)));
                float ig = 1.0f / (1.0f + expf(-(aI[m][r] + mk*tI)));
                float ng = tanhf(aNX[m][r] + mk*tN + rg * aNH[m][r]);
                float h  = hs[((long)row*NU + u)*NH + col];
                ov = f2bf(ng + ig * (h - ng));
            }
            hnbf[(long)u*NB*KH + (long)row*KH + col] = ov;
        }
    }
}

// ================= generic 128x128 bf16 MFMA GEMM (BK=64, 2-buf counted) ====
// EPI=0: f32 store; EPI=1: final out blend; EPI=2: bf16 store
template<int EPI>
__global__ __launch_bounds__(256, 2)
void mfgemm_kernel(const u16* __restrict__ A, long sAu, int lda,
                   const u16* __restrict__ Bw, long sBu, int ldb,
                   float* __restrict__ Cf, u16* __restrict__ C16,
                   long sCu, int ldc, int ksteps,      // ksteps in BK=64 units
                   const float* __restrict__ maskf,
                   const u16* __restrict__ hnbf,
                   const float* __restrict__ hs,
                   int bbase)
{
    const int u  = blockIdx.z;
    const int m0 = blockIdx.x * 128;
    const int n0 = blockIdx.y * 128;
    const int tid = threadIdx.x;
    const int wid = tid >> 6, lane = tid & 63;
    const int wm = wid >> 1, wn = wid & 1;
    const int lrow = lane & 15, lkq = lane >> 4;
    const int l8 = lane & 7, lr8 = lane >> 3;
    const int rsw = lrow & 7;

    __shared__ __align__(16) u16 As[2][128 * 64];
    __shared__ __align__(16) u16 Bs[2][128 * 64];

    const u16* Au = A + (long)u * sAu;
    const u16* Bu = Bw + (long)u * sBu;

    f32x4 acc[4][4];
    #pragma unroll
    for (int m = 0; m < 4; m++)
        #pragma unroll
        for (int n = 0; n < 4; n++) acc[m][n] = (f32x4){0,0,0,0};

#define MSTAGE(BUF, KS) do {                                                  \
        const long kk0 = (long)(KS) * 64;                                     \
        _Pragma("unroll")                                                     \
        for (int i2 = 0; i2 < 4; i2++) {                                      \
            int rw = i2*32 + wid*8 + lr8;                                     \
            int co = ((l8 ^ (rw & 7)) * 8);                                   \
            gl_lds16(Au + (long)(m0 + rw)*lda + kk0 + co,                     \
                     &As[BUF][(i2*32 + wid*8) * 64]);                         \
            gl_lds16(Bu + (long)(n0 + rw)*ldb + kk0 + co,                     \
                     &Bs[BUF][(i2*32 + wid*8) * 64]);                         \
        }                                                                     \
    } while (0)

#define MCOMPUTE(BUF) do {                                                    \
        __builtin_amdgcn_s_setprio(1);                                        \
        _Pragma("unroll")                                                     \
        for (int ks2 = 0; ks2 < 2; ks2++) {                                   \
            const int cofs = (((ks2*4 + lkq) ^ rsw) * 8);                     \
            short8 af[4], bfr[4];                                             \
            _Pragma("unroll")                                                 \
            for (int m = 0; m < 4; m++)                                       \
                af[m] = *(const short8*)&As[BUF][(wm*64 + m*16 + lrow)*64 + cofs]; \
            _Pragma("unroll")                                                 \
            for (int n = 0; n < 4; n++)                                       \
                bfr[n] = *(const short8*)&Bs[BUF][(wn*64 + n*16 + lrow)*64 + cofs]; \
            _Pragma("unroll")                                                 \
            for (int m = 0; m < 4; m++)                                       \
                _Pragma("unroll")                                             \
                for (int n = 0; n < 4; n++)                                   \
                    acc[m][n] = __builtin_amdgcn_mfma_f32_16x16x32_bf16(af[m], bfr[n], acc[m][n], 0, 0, 0); \
        }                                                                     \
        __builtin_amdgcn_s_setprio(0);                                        \
    } while (0)

#define MPH(BUF, T, W) do {                                                   \
        if ((T) + 1 < ksteps) MSTAGE((BUF)^1, (T)+1);                         \
        WAITVM(W); SBAR();                                                    \
        MCOMPUTE(BUF);                                                        \
        WAITLG(); SBAR();                                                     \
    } while (0)

    MSTAGE(0, 0);
    int t = 0;
    for (; t + 2 < ksteps; t += 2) { MPH(0, t, 8); MPH(1, t+1, 8); }
    if (t + 2 == ksteps) { MPH(0, t, 8); MPH(1, t+1, 0); }
    else                 { MPH(0, t, 0); }   // odd tail (used by M-GEMM, ksteps=7)
#undef MPH
#undef MCOMPUTE
#undef MSTAGE

    #pragma unroll
    for (int m = 0; m < 4; m++) {
        #pragma unroll
        for (int r = 0; r < 4; r++) {
            int row = m0 + wm*64 + m*16 + lkq*4 + r;
            #pragma unroll
            for (int n = 0; n < 4; n++) {
                int col = n0 + wn*64 + n*16 + lrow;
                float v = acc[m][n][r];
                if (EPI == 0) {
                    Cf[(long)u*sCu + (long)row*ldc + col] = v;
                } else if (EPI == 2) {
                    C16[(long)u*sCu + (long)row*ldc + col] = f2bf(v);
                } else {
                    if (col < NH) {
                        int b = bbase + row;
                        long o = ((long)b*NU + u)*NH + col;
                        float mk = maskf[(long)b*NU + u];
                        float hv = bf2f(hnbf[(long)u*NB*KH + (long)b*KH + col]);
                        Cf[o] = (mk > 0.5f) ? (v + hv) : hs[o];
                    }
                }
            }
        }
    }
}

// ================= K7: attention weights (two b per block) =================
__global__ __launch_bounds__(256)
void attw_kernel(const float* __restrict__ qk, const float* __restrict__ maskf,
                 float* __restrict__ attw)
{
    const int b2 = blockIdx.x * 2;               // this block handles b2, b2+1
    const int t = threadIdx.x;
    __shared__ float qks[2][NU * QKW];           // 12KB
    __shared__ float lg[2][NCH][NU][NU];

    for (int i = t; i < 2 * NU * QKW / 4; i += 256) {
        int bb = i / (NU * QKW / 4), j = i % (NU * QKW / 4);
        *(float4*)&qks[bb][j * 4] =
            *(const float4*)&qk[(long)(b2 + bb) * NU * QKW + j * 4];
    }
    __syncthreads();

    // 288 logit items over 256 threads: STRIDED loop (r15 bug: plain guard
    // left items 256..287 uncomputed -> garbage lg[1][3][...])
    for (int i = t; i < 2 * NCH * NU * NU; i += 256) {
        int bb = i / 144, r = i % 144;
        int h = r / 36, uq = (r % 36) / 6, un = r % 6;
        const float* qp = &qks[bb][uq * QKW + h * 32];
        const float* kp = &qks[bb][un * QKW + 128 + h * 32];
        float s = 0;
        #pragma unroll
        for (int i2 = 0; i2 < 32; i2++) s = fmaf(qp[i2], kp[i2], s);
        lg[bb][h][uq][un] = s * 0.17677669529663687f;
    }
    __syncthreads();
    if (t < 2 * NCH * NU) {
        int bb = t / (NCH * NU), r = t % (NCH * NU);
        int h = r / NU, uq = r % NU;
        int b = b2 + bb;
        float mx = -1e30f;
        #pragma unroll
        for (int n = 0; n < NU; n++) mx = fmaxf(mx, lg[bb][h][uq][n]);
        float e[NU], se = 0;
        #pragma unroll
        for (int n = 0; n < NU; n++) { e[n] = expf(lg[bb][h][uq][n] - mx); se += e[n]; }
        float m = maskf[(long)b*NU + uq];
        float inv = m / se;
        #pragma unroll
        for (int n = 0; n < NU; n++)
            attw[(((long)b*NCH + h)*NU + uq)*NU + n] = e[n] * inv;
    }
}

// ================= ctx = att @ v, IN-PLACE on the v buffer ==================
__global__ __launch_bounds__(256)
void ctx2_kernel(const float* __restrict__ attw, u16* vc, int bbase)
{
    __shared__ float att_s[32][NCH * NU * NU];   // [bl][h*36+u*6+n] = 144
    const int c0 = blockIdx.x * 64;
    const int b0 = blockIdx.y * 32;
    const int tid = threadIdx.x;

    for (int i = tid; i < 32 * 144; i += 256) {
        int bl = i / 144, j = i % 144;
        att_s[bl][j] = attw[(long)(bbase + b0 + bl) * 144 + j];
    }
    __syncthreads();

    const int bl = tid >> 3;
    const int c  = c0 + (tid & 7) * 8;
    const long rowbase = (long)(b0 + bl) * NU;   // chunk-local

    if (c >= VW) {   // pad columns -> zero
        short8 z = {0,0,0,0,0,0,0,0};
        #pragma unroll
        for (int u = 0; u < NU; u++)
            *(short8*)&vc[(rowbase + u) * VN + c] = z;
        return;
    }
    const int h = c / CVS;
    const float* aw = &att_s[bl][h * 36];

    float vf[NU][8];
    #pragma unroll
    for (int n = 0; n < NU; n++) {
        short8 vv = *(const short8*)&vc[(rowbase + n) * VN + c];
        #pragma unroll
        for (int i = 0; i < 8; i++) vf[n][i] = bf2f((u16)vv[i]);
    }
    #pragma unroll
    for (int u = 0; u < NU; u++) {
        float acc[8] = {};
        #pragma unroll
        for (int n = 0; n < NU; n++) {
            float a = aw[u * 6 + n];
            #pragma unroll
            for (int i = 0; i < 8; i++) acc[i] = fmaf(a, vf[n][i], acc[i]);
        }
        short8 o;
        #pragma unroll
        for (int i = 0; i < 8; i++) o[i] = (short)f2bf(acc[i]);
        *(short8*)&vc[(rowbase + u) * VN + c] = o;
    }
}

// ================= host launcher =================
extern "C" void kernel_launch(void* const* d_in, const int* in_sizes, int n_in,
                              void* d_out, int out_size, void* d_ws, size_t ws_size,
                              hipStream_t stream)
{
    const float* x    = (const float*)d_in[0];
    const float* hs   = (const float*)d_in[1];
    const float* Wk   = (const float*)d_in[2];
    const float* bk   = (const float*)d_in[3];
    const float* Wv   = (const float*)d_in[4];
    const float* bv   = (const float*)d_in[5];
    const float* Wq   = (const float*)d_in[6];
    const float* x2h  = (const float*)d_in[7];
    const float* h2h  = (const float*)d_in[8];
    const float* Wq_  = (const float*)d_in[9];
    const float* Wk_  = (const float*)d_in[10];
    const float* Wv_  = (const float*)d_in[11];
    const float* Wout = (const float*)d_in[12];
    float* out = (float*)d_out;
    float* ws  = (float*)d_ws;

    float* kv    = ws + OFF_KV;
    float* qry   = ws + OFF_QRY;
    float* c0b   = ws + OFF_C0;
    float* c1b   = ws + OFF_C1;
    float* maskf = ws + OFF_MASK;
    float* qk    = ws + OFF_QK;
    float* attw  = ws + OFF_ATTW;
    u16*   hnbf  = (u16*)(ws + OFF_HNBF);
    u16*   wqk   = (u16*)(ws + OFF_WQK);
    u16*   wv    = (u16*)(ws + OFF_WV);
    u16*   wout  = (u16*)(ws + OFF_WOUT);
    u16*   wvb   = (u16*)(ws + OFF_WVB);
    float* tvec  = ws + OFF_TVEC;
    u16*   wgru2 = (u16*)(ws + OFF_WGRU2);
    u16*   agru2 = (u16*)(ws + OFF_AGRU2);
    u16*   wgx   = (u16*)(ws + OFF_WGRUX);  // aliased with agru2 (dead first)
    u16*   vcbuf = (u16*)(ws + OFF_VBUF);   // aliases wgru2+agru2 (chunk phase)

    // 1) weight conversions/transposes (k-pads zero-written by wtrans)
    // Wq_ (g=0) + Wk_ (g=1) fused: z = u*2+g, dest row offset g*128
    wtrans_kernel<<<dim3(20, 4, NU*2), 256, 0, stream>>>(
        Wq_, Wk_, (long)NH*128, 128, 0, NH, 128,
        wqk, (long)QKW*KH, KH, 0, 0, 2, 0, 128);
    wtrans_kernel<<<dim3(20, 75, NU), 256, 0, stream>>>(
        Wv_, nullptr, (long)NH*VW, VW, 0, NH, VW,
        wv, (long)VN*KH, KH, 0, 0, 1, 0, 0);
    wtrans_kernel<<<dim3(76, 19, NU), 256, 0, stream>>>(
        Wout, nullptr, (long)VW*NH, NH, 0, VW, NH,
        wout, (long)NGATE*VN, VN, 0, 0, 1, 0, 0);
    // x2h^T -> wgx [NU][1920][448]  (g folded into grid.z)
    wtrans_kernel<<<dim3(KXP/32, 19, NU*3), 256, 0, stream>>>(
        x2h, nullptr, (long)IVS*3*NH, 3*NH, 0, IVS, NH,
        wgx, (long)NROWS3*KXP, KXP, 0, 0, 3, NH, NGATE);
    // h2h^T -> wgru2 k 256..895
    wtrans_kernel<<<dim3(20, 19, NU*3), 256, 0, stream>>>(
        h2h, nullptr, (long)NH*3*NH, 3*NH, 0, NH, NH,
        wgru2, (long)NROWS3*KG2, KG2, 0, HOFS2, 3, NH, NGATE);
    // fused: t[u] = x2h^T @ bv (wave/row) + Wv -> bf16 [256][448]
    tvec_wvb_kernel<<<TVEC_BLKS + WVB_BLKS, 256, 0, stream>>>(
        wgx, bv, tvec, Wv, wvb);
    // M^T[u] = x2h^T @ Wv : wgru2 k 0..255   (ksteps = 7, odd tail)
    mfgemm_kernel<2><<<dim3(NROWS3/128, 2, NU), 256, 0, stream>>>(
        wgx, (long)NROWS3*KXP, KXP, wvb, 0L, KXP,
        nullptr, wgru2, (long)NROWS3*KG2, KG2, KXP/64, nullptr, nullptr, nullptr, 0);

    // 2) f32 front-end: qry (z=0..5) + k0 (z=6) fused
    gemm_qry_kernel<<<dim3(NB/64, 1, NU + 1), 256, 0, stream>>>(
        hs, Wq, x, Wk, bk, qry, kv);
    score_kernel<<<NB, 64, 0, stream>>>(qry, kv, bk, c0b, c1b, maskf);

    // 3) GRU A prep (AFTER M-GEMM+tvec: agru2 overwrites wgx) + GRU MFMA
    {
        long total = (long)NU * NB * (KG2/8);
        prep_gruA_kernel<<<(unsigned)((total + 255)/256), 256, 0, stream>>>(
            x, hs, c0b, agru2);
    }
    gru_mfma_kernel<<<dim3(NB/128, NGATE/32, NU), 256, 0, stream>>>(
        agru2, wgru2, tvec, maskf, hs, hnbf);

    // 4) qk projection (MFMA) + attention weights
    mfgemm_kernel<0><<<dim3(NB/128, QKW/128, NU), 256, 0, stream>>>(
        hnbf, (long)NB*KH, KH, wqk, (long)QKW*KH, KH,
        qk, nullptr, (long)QKW, NU*QKW, KH/64, nullptr, nullptr, nullptr, 0);
    attw_kernel<<<NB/2, 256, 0, stream>>>(qk, maskf, attw);

    // 5) chunked v / ctx(in-place) / out  (BC=2048, 2 chunks)
    for (int ch = 0; ch < NCHUNK; ch++) {
        mfgemm_kernel<2><<<dim3(BC/128, VN/128, NU), 256, 0, stream>>>(
            hnbf + (long)ch*BC*KH, (long)NB*KH, KH, wv, (long)VN*KH, KH,
            nullptr, vcbuf, (long)VN, NU*VN, KH/64, nullptr, nullptr, nullptr, 0);
        ctx2_kernel<<<dim3(VN/64, BC/32), 256, 0, stream>>>(
            attw, vcbuf, ch*BC);
        mfgemm_kernel<1><<<dim3(BC/128, NGATE/128, NU), 256, 0, stream>>>(
            vcbuf, (long)VN, NU*VN, wout, (long)NGATE*VN, VN,
            out, nullptr, 0, 0, VN/64, maskf, hnbf, hs, ch*BC);
    }
}